// Round 3
// baseline (4592.008 us; speedup 1.0000x reference)
//
#include <hip/hip_runtime.h>
#include <hip/hip_bf16.h>

typedef unsigned short u16;
typedef unsigned int u32;

// ---------------- LayerNorm (f32 in) : writes h (f32) and optionally acc = x ----
__global__ __launch_bounds__(256) void k_ln(const float* __restrict__ x, const float* __restrict__ g,
    const float* __restrict__ b, float* __restrict__ hout, float* __restrict__ acc) {
  int token = blockIdx.x * 4 + (threadIdx.x >> 6);
  int lane = threadIdx.x & 63;
  long base = (long)token * 64 + lane;
  float v = x[base];
  float s = v;
#pragma unroll
  for (int o = 32; o; o >>= 1) s += __shfl_xor(s, o);
  float m = s * 0.015625f;
  float d = v - m;
  float q = d * d;
#pragma unroll
  for (int o = 32; o; o >>= 1) q += __shfl_xor(q, o);
  float r = rsqrtf(q * 0.015625f + 1e-5f);
  hout[base] = d * r * g[lane] + b[lane];
  if (acc) acc[base] = v;
}

// ---------------- Spatial window attention: one block per (window, head) --------
// windows: (b, d0<4, h0<16, w0<16), tokens n = dz*49+hy*7+wx (98), head dim 16
// LDS strides padded for bank-conflict-free access:
//   region A (9702): x as 98x65 during phase 0/1, scores as 98x99 after
//   region B (5880): Q/K/V each 98 rows x stride 20
//   region C (3072): staged qkv weights for this head, [part][c][16]
__global__ __launch_bounds__(256) void k_sattn(const float* __restrict__ h, const float* __restrict__ qw,
    const float* __restrict__ qb, const float* __restrict__ rpb, float* __restrict__ aout) {
  __shared__ __align__(16) float smem[18656];
  float* sA = smem;            // 9702
  float* sQ = smem + 9702;     // 98*20
  float* sK = sQ + 1960;
  float* sV = sK + 1960;
  float* sW = sV + 1960;       // 3072 = 3*64*16
  int tid = threadIdx.x;
  int blk = blockIdx.x;
  int hd = blk & 3;
  int wi = blk >> 2;
  int b = wi >> 10, d0 = (wi >> 8) & 3, h0 = (wi >> 4) & 15, w0 = wi & 15;

  // phase 0a: load window tokens (98 x 64) at stride 65
  for (int i = tid; i < 6272; i += 256) {
    int n = i >> 6, c = i & 63;
    int dz = n / 49, r = n - dz * 49, hy = r / 7, wx = r - hy * 7;
    long p = ((long)(b * 8 + d0 * 2 + dz) * 112 + (h0 * 7 + hy)) * 112 + (w0 * 7 + wx);
    sA[n * 65 + c] = h[p * 64 + c];
  }
  // phase 0b: stage this head's qkv weight columns: sW[(part*64+c)*16 + jj]
  for (int i = tid; i < 3072; i += 256) {
    int jj = i & 15, c = (i >> 4) & 63, part = i >> 10;
    sW[i] = qw[c * 192 + part * 64 + hd * 16 + jj];
  }
  __syncthreads();
  // phase 1: qkv, 8 output columns per item (98 rows x 6 col-groups)
  for (int i = tid; i < 588; i += 256) {
    int n = i / 6, g = i - n * 6;
    int part = g >> 1, j8 = (g & 1) << 3;
    int colbase = part * 64 + hd * 16 + j8;
    float4 b0 = *(const float4*)(qb + colbase);
    float4 b1 = *(const float4*)(qb + colbase + 4);
    float a0 = b0.x, a1 = b0.y, a2 = b0.z, a3 = b0.w;
    float a4 = b1.x, a5 = b1.y, a6 = b1.z, a7 = b1.w;
    const float* xr = &sA[n * 65];
    const float* wr = &sW[part * 1024 + j8];
    for (int c = 0; c < 64; c++) {
      float xv = xr[c];
      float4 w0 = *(const float4*)(wr + c * 16);
      float4 w1 = *(const float4*)(wr + c * 16 + 4);
      a0 += xv * w0.x; a1 += xv * w0.y; a2 += xv * w0.z; a3 += xv * w0.w;
      a4 += xv * w1.x; a5 += xv * w1.y; a6 += xv * w1.z; a7 += xv * w1.w;
    }
    float* dst = part == 0 ? sQ : (part == 1 ? sK : sV);
    float sc = part == 0 ? 0.25f : 1.0f;
    float* dp = dst + n * 20 + j8;
    *(float4*)dp = make_float4(a0 * sc, a1 * sc, a2 * sc, a3 * sc);
    *(float4*)(dp + 4) = make_float4(a4 * sc, a5 * sc, a6 * sc, a7 * sc);
  }
  __syncthreads();
  // phase 2: scores + relative position bias (scores at stride 99 over sA)
  for (int i = tid; i < 2450; i += 256) {
    int n = i / 25, mc = i - n * 25;
    int m0 = mc * 4;
    float4 q0 = *(float4*)&sQ[n * 20], q1 = *(float4*)&sQ[n * 20 + 4];
    float4 q2 = *(float4*)&sQ[n * 20 + 8], q3 = *(float4*)&sQ[n * 20 + 12];
    int dzn = n / 49, rn = n - dzn * 49, hyn = rn / 7, wxn = rn - hyn * 7;
    int mend = (m0 + 4 > 98) ? 98 : m0 + 4;
    for (int m = m0; m < mend; m++) {
      float4 k0 = *(float4*)&sK[m * 20], k1 = *(float4*)&sK[m * 20 + 4];
      float4 k2 = *(float4*)&sK[m * 20 + 8], k3 = *(float4*)&sK[m * 20 + 12];
      float sv = q0.x * k0.x + q0.y * k0.y + q0.z * k0.z + q0.w * k0.w
               + q1.x * k1.x + q1.y * k1.y + q1.z * k1.z + q1.w * k1.w
               + q2.x * k2.x + q2.y * k2.y + q2.z * k2.z + q2.w * k2.w
               + q3.x * k3.x + q3.y * k3.y + q3.z * k3.z + q3.w * k3.w;
      int dzm = m / 49, rm = m - dzm * 49, hym = rm / 7, wxm = rm - hym * 7;
      int idx = (dzn - dzm + 1) * 169 + (hyn - hym + 6) * 13 + (wxn - wxm + 6);
      sA[n * 99 + m] = sv + rpb[idx * 4 + hd];
    }
  }
  __syncthreads();
  // phase 3: softmax per row (stride 99 -> conflict-free across lanes)
  if (tid < 98) {
    float* row = &sA[tid * 99];
    float mx = -1e30f;
    for (int m = 0; m < 98; m++) mx = fmaxf(mx, row[m]);
    float sum = 0.f;
    for (int m = 0; m < 98; m++) { float e = __expf(row[m] - mx); row[m] = e; sum += e; }
    float inv = 1.f / sum;
    for (int m = 0; m < 98; m++) row[m] *= inv;
  }
  __syncthreads();
  // phase 4: P @ V -> attn out (pre-projection), layout (window, n, 64)
  for (int i = tid; i < 392; i += 256) {
    int n = i >> 2, e0 = (i & 3) << 2;
    float a0 = 0, a1 = 0, a2 = 0, a3 = 0;
    const float* prow = &sA[n * 99];
    for (int m = 0; m < 98; m++) {
      float p = prow[m];
      float4 vv = *(float4*)&sV[m * 20 + e0];
      a0 += p * vv.x; a1 += p * vv.y; a2 += p * vv.z; a3 += p * vv.w;
    }
    long ob = ((long)wi * 98 + n) * 64 + hd * 16 + e0;
    aout[ob] = a0; aout[ob + 1] = a1; aout[ob + 2] = a2; aout[ob + 3] = a3;
  }
}

// ---------------- Spatial projection: (nw*98,64)@(64,64) scatter-add into acc ---
__global__ __launch_bounds__(256) void k_sproj(const float* __restrict__ ain, const float* __restrict__ pw,
    const float* __restrict__ pb, float* __restrict__ acc) {
  __shared__ float srow[4][64];
  int wv = threadIdx.x >> 6, c = threadIdx.x & 63;
  int row = blockIdx.x * 4 + wv;
  srow[wv][c] = ain[(long)row * 64 + c];
  __syncthreads();
  float a = pb[c];
  const float* xr = srow[wv];
  const float* wp = pw + c;
  for (int k = 0; k < 64; k++) a += xr[k] * wp[k * 64];
  int wi = row / 98, n = row - wi * 98;
  int b = wi >> 10, d0 = (wi >> 8) & 3, h0 = (wi >> 4) & 15, w0 = wi & 15;
  int dz = n / 49, r2 = n - dz * 49, hy = r2 / 7, wx = r2 - hy * 7;
  long p = ((long)(b * 8 + d0 * 2 + dz) * 112 + (h0 * 7 + hy)) * 112 + (w0 * 7 + wx);
  acc[p * 64 + c] += a;
}

// ---------------- Temporal attention: one wave per pixel sequence (D=8) ---------
// LDS per wave: xt 8x65=520 | qkv 8x97=776 | sp 64 | o 8x33=264  => 1624 floats
__global__ __launch_bounds__(256) void k_tattn(const float* __restrict__ h, const float* __restrict__ qw,
    const float* __restrict__ qb, const float* __restrict__ rpbt, const float* __restrict__ pw,
    const float* __restrict__ pb, float* __restrict__ acc) {
  __shared__ float sm[4][1624];
  int wv = threadIdx.x >> 6, lane = threadIdx.x & 63;
  int s = blockIdx.x * 4 + wv;
  int b = s / 12544, rr = s - b * 12544, hy = rr / 112, wx = rr - hy * 112;
  float* xt = sm[wv];       // 8 x stride 65
  float* qkv = xt + 520;    // 8 x stride 97
  float* sp = qkv + 776;    // 64
  float* o = sp + 64;       // 8 x stride 33
  long pbase = ((long)b * 896 + hy) * 112 + wx;   // pos of token n = pbase + n*12544
  for (int i = lane; i < 512; i += 64) {
    int n = i >> 6, c = i & 63;
    xt[n * 65 + c] = h[(pbase + (long)n * 12544) * 64 + c];
  }
  __syncthreads();
  // qkv (8 x 96)
  for (int i = lane; i < 192; i += 64) {
    int n = i / 24, c4 = (i - n * 24) * 4;
    float4 a4 = *(const float4*)(qb + c4);
    float a0 = a4.x, a1 = a4.y, a2 = a4.z, a3 = a4.w;
    const float* xr = &xt[n * 65];
    const float* wp = qw + c4;
    for (int c = 0; c < 64; c++) {
      float xv = xr[c];
      float4 w4 = *(const float4*)(wp + c * 96);
      a0 += xv * w4.x; a1 += xv * w4.y;
      a2 += xv * w4.z; a3 += xv * w4.w;
    }
    float sc = (c4 < 32) ? 0.25f : 1.f;
    int ob = n * 97 + c4;
    qkv[ob] = a0 * sc; qkv[ob + 1] = a1 * sc; qkv[ob + 2] = a2 * sc; qkv[ob + 3] = a3 * sc;
  }
  __syncthreads();
  int n8 = lane >> 3, m8 = lane & 7;
  for (int hd = 0; hd < 4; hd++) {
    float sc = 0.f;
    const float* qr = &qkv[n8 * 97 + hd * 8];
    const float* kr = &qkv[m8 * 97 + 32 + hd * 8];
#pragma unroll
    for (int e = 0; e < 8; e++) sc += qr[e] * kr[e];
    sc += rpbt[(n8 - m8 + 7) * 4 + hd];
    sp[lane] = sc;
    __syncthreads();
    if (lane < 8) {
      float* row = &sp[lane * 8];
      float mx = -1e30f;
      for (int m = 0; m < 8; m++) mx = fmaxf(mx, row[m]);
      float sum = 0.f;
      for (int m = 0; m < 8; m++) { float e = __expf(row[m] - mx); row[m] = e; sum += e; }
      float inv = 1.f / sum;
      for (int m = 0; m < 8; m++) row[m] *= inv;
    }
    __syncthreads();
    float a = 0.f;
    const float* prow = &sp[n8 * 8];
#pragma unroll
    for (int m = 0; m < 8; m++) a += prow[m] * qkv[m * 97 + 64 + hd * 8 + m8];
    o[n8 * 33 + hd * 8 + m8] = a;
    __syncthreads();
  }
  // projection (32 -> 64), add into acc
  for (int i = lane; i < 128; i += 64) {
    int n = i >> 4, c4 = (i & 15) << 2;
    float4 a4 = *(const float4*)(pb + c4);
    float a0 = a4.x, a1 = a4.y, a2 = a4.z, a3 = a4.w;
    const float* orow = &o[n * 33];
    const float* wp = pw + c4;
    for (int k = 0; k < 32; k++) {
      float ov = orow[k];
      float4 w4 = *(const float4*)(wp + k * 64);
      a0 += ov * w4.x; a1 += ov * w4.y; a2 += ov * w4.z; a3 += ov * w4.w;
    }
    long ab = (pbase + (long)n * 12544) * 64 + c4;
    acc[ab] += a0; acc[ab + 1] += a1; acc[ab + 2] += a2; acc[ab + 3] += a3;
  }
}

// ---------------- Direct 3x3x3 conv, channels-last, 32ci -> 32co ----------------
// grid (2, 112, 16=b*8+d); block 256 = 8 w-groups x 32 co; each thread 8 outputs
__global__ __launch_bounds__(256) void k_conv(const float* __restrict__ in, int ics,
    const float* __restrict__ wgt, const float* __restrict__ bias,
    const float* __restrict__ addsrc, int acs, float* __restrict__ out, int lrelu) {
  __shared__ __align__(16) float s_in[32 * 68];
  __shared__ float s_w[32 * 97];
  int tid = threadIdx.x;
  int co = tid & 31, ws8 = tid >> 5;
  int wtile = blockIdx.x, hh = blockIdx.y, bz = blockIdx.z;
  int d = bz & 7, bb = bz >> 3;
  int wbase = wtile * 64;
  float acc[8];
#pragma unroll
  for (int q = 0; q < 8; q++) acc[q] = 0.f;
  for (int kd = 0; kd < 3; kd++) {
    int zd = d + kd - 1;
    if (zd < 0 || zd > 7) continue;
    for (int kh = 0; kh < 3; kh++) {
      int yy = hh + kh - 1;
      if (yy < 0 || yy > 111) continue;
      __syncthreads();
      int prow = ((bb * 8 + zd) * 112 + yy) * 112;
      for (int i = tid; i < 2112; i += 256) {
        int ci = i & 31, j = i >> 5;
        int w = wbase - 1 + j;
        float v = 0.f;
        if (w >= 0 && w < 112) v = in[(long)(prow + w) * ics + ci];
        s_in[ci * 68 + j] = v;
      }
      for (int i = tid; i < 3072; i += 256) {
        int c2 = i / 96, r = i - c2 * 96;
        int ci = r / 3, kw = r - ci * 3;
        s_w[c2 * 97 + r] = wgt[(c2 * 32 + ci) * 27 + kd * 9 + kh * 3 + kw];
      }
      __syncthreads();
      int jb = ws8 * 8;
      for (int ci = 0; ci < 32; ci++) {
        const float* ip = &s_in[ci * 68 + jb];
        float4 A = *(const float4*)ip;
        float4 Bv = *(const float4*)(ip + 4);
        float2 Cv = *(const float2*)(ip + 8);
        float v[10] = {A.x, A.y, A.z, A.w, Bv.x, Bv.y, Bv.z, Bv.w, Cv.x, Cv.y};
        const float* wr = &s_w[co * 97 + ci * 3];
        float w0 = wr[0], w1 = wr[1], w2 = wr[2];
#pragma unroll
        for (int q = 0; q < 8; q++)
          acc[q] += v[q] * w0 + v[q + 1] * w1 + v[q + 2] * w2;
      }
    }
  }
  float bv = bias[co];
  int w00 = wbase + ws8 * 8;
  int pcol = (bz * 112 + hh) * 112;
#pragma unroll
  for (int q = 0; q < 8; q++) {
    int w = w00 + q;
    if (w < 112) {
      float vv = acc[q] + bv;
      if (lrelu) vv = vv > 0.f ? vv : 0.01f * vv;
      long pos = pcol + w;
      if (addsrc) vv += addsrc[pos * acs + co];
      out[pos * 32 + co] = vv;
    }
  }
}

// ---------------- x2 += y1 (in place in h2's channel 32..63) --------------------
__global__ __launch_bounds__(256) void k_addx2(float* __restrict__ h2, const float* __restrict__ y1) {
  long i = (long)blockIdx.x * 256 + threadIdx.x;
  long pos = i >> 5;
  int c = (int)(i & 31);
  h2[pos * 64 + 32 + c] += y1[i];
}

// ---------------- out = acc + concat(y1,y2) -------------------------------------
__global__ __launch_bounds__(256) void k_final(const float* __restrict__ acc, const float* __restrict__ y1,
    const float* __restrict__ y2, float* __restrict__ out) {
  long i = (long)blockIdx.x * 256 + threadIdx.x;
  long pos = i >> 6;
  int c = (int)(i & 63);
  float v = acc[i] + (c < 32 ? y1[pos * 32 + c] : y2[pos * 32 + c - 32]);
  out[i] = v;
}

extern "C" void kernel_launch(void* const* d_in, const int* in_sizes, int n_in,
                              void* d_out, int out_size, void* d_ws, size_t ws_size,
                              hipStream_t stream) {
  const float* x        = (const float*)d_in[0];
  // d_in[1] mask_matrix: unused (all zeros in reference path)
  const float* g1       = (const float*)d_in[2];
  const float* b1       = (const float*)d_in[3];
  const float* rpb_s    = (const float*)d_in[4];
  const float* qkv_w_s  = (const float*)d_in[5];
  const float* qkv_b_s  = (const float*)d_in[6];
  const float* proj_w_s = (const float*)d_in[7];
  const float* proj_b_s = (const float*)d_in[8];
  const float* rpb_t    = (const float*)d_in[9];
  const float* qkv_w_t  = (const float*)d_in[10];
  const float* qkv_b_t  = (const float*)d_in[11];
  const float* proj_w_t = (const float*)d_in[12];
  const float* proj_b_t = (const float*)d_in[13];
  const float* g2       = (const float*)d_in[14];
  const float* b2       = (const float*)d_in[15];
  const float* c1w = (const float*)d_in[16];
  const float* c1b = (const float*)d_in[17];
  const float* c2w = (const float*)d_in[18];
  const float* c2b = (const float*)d_in[19];
  const float* c3w = (const float*)d_in[20];
  const float* c3b = (const float*)d_in[21];
  const float* c4w = (const float*)d_in[22];
  const float* c4b = (const float*)d_in[23];

  // workspace layout (fp32): acc | hbuf(h/h2) | tbuf | y1 | y2  = ~180 MB
  float* acc  = (float*)d_ws;
  float* hbuf = acc + 12845056;
  float* tbuf = hbuf + 12845056;
  float* y1   = tbuf + 6422528;
  float* y2   = y1 + 6422528;
  float* aout = tbuf;  // spans tbuf..y1 (12.85M floats), dead before convs start

  // 1. LN1: h = LN(x); acc = x
  k_ln<<<50176, 256, 0, stream>>>(x, g1, b1, hbuf, acc);
  // 2. spatial window attention (qkv + softmax + PV) -> aout
  k_sattn<<<8192, 256, 0, stream>>>(hbuf, qkv_w_s, qkv_b_s, rpb_s, aout);
  // 3. spatial projection, scatter-add into acc
  k_sproj<<<50176, 256, 0, stream>>>(aout, proj_w_s, proj_b_s, acc);
  // 4. temporal attention, add into acc
  k_tattn<<<6272, 256, 0, stream>>>(hbuf, qkv_w_t, qkv_b_t, rpb_t, proj_w_t, proj_b_t, acc);
  // 5. LN2: h2 = LN(acc)   (channels-last kept; reference transpose is layout-only)
  k_ln<<<50176, 256, 0, stream>>>(acc, g2, b2, hbuf, nullptr);
  // 6. conv path 1: t = lrelu(conv(x1)); y1 = x1 + conv(t)
  k_conv<<<dim3(2, 112, 16), 256, 0, stream>>>(hbuf, 64, c1w, c1b, nullptr, 0, tbuf, 1);
  k_conv<<<dim3(2, 112, 16), 256, 0, stream>>>(tbuf, 32, c2w, c2b, hbuf, 64, y1, 0);
  // 7. x2 += y1 (in place)
  k_addx2<<<25088, 256, 0, stream>>>(hbuf, y1);
  // 8. conv path 2: t = lrelu(conv(x2b)); y2 = x2b + conv(t)
  k_conv<<<dim3(2, 112, 16), 256, 0, stream>>>(hbuf + 32, 64, c3w, c3b, nullptr, 0, tbuf, 1);
  k_conv<<<dim3(2, 112, 16), 256, 0, stream>>>(tbuf, 32, c4w, c4b, hbuf + 32, 64, y2, 0);
  // 9. out = acc + concat(y1, y2)
  k_final<<<50176, 256, 0, stream>>>(acc, y1, y2, (float*)d_out);
}

// Round 4
// 3650.654 us; speedup vs baseline: 1.2579x; 1.2579x over previous
//
#include <hip/hip_runtime.h>
#include <hip/hip_bf16.h>

typedef unsigned short u16;
typedef unsigned int u32;

// ---------------- LayerNorm (f32 in) : writes h (f32) and optionally acc = x ----
__global__ __launch_bounds__(256) void k_ln(const float* __restrict__ x, const float* __restrict__ g,
    const float* __restrict__ b, float* __restrict__ hout, float* __restrict__ acc) {
  int token = blockIdx.x * 4 + (threadIdx.x >> 6);
  int lane = threadIdx.x & 63;
  long base = (long)token * 64 + lane;
  float v = x[base];
  float s = v;
#pragma unroll
  for (int o = 32; o; o >>= 1) s += __shfl_xor(s, o);
  float m = s * 0.015625f;
  float d = v - m;
  float q = d * d;
#pragma unroll
  for (int o = 32; o; o >>= 1) q += __shfl_xor(q, o);
  float r = rsqrtf(q * 0.015625f + 1e-5f);
  hout[base] = d * r * g[lane] + b[lane];
  if (acc) acc[base] = v;
}

// ---------------- Spatial window attention: one block per (window, head) --------
// windows: (b, d0<4, h0<16, w0<16), tokens n = dz*49+hy*7+wx (98), head dim 16
// LDS strides padded for bank-conflict-free access (round-3 fix, kept):
//   region A (9702): x as 98x65 during phase 0/1, scores as 98x99 after
//   region B (5880): Q/K/V each 98 rows x stride 20
// Weights read from GLOBAL (L1-resident, VMEM pipe) — round-3 LDS staging of
// weights put them on the already-saturated DS pipe and tripled duration.
__global__ __launch_bounds__(256) void k_sattn(const float* __restrict__ h, const float* __restrict__ qw,
    const float* __restrict__ qb, const float* __restrict__ rpb, float* __restrict__ aout) {
  __shared__ __align__(16) float smem[15582];
  float* sA = smem;            // 9702
  float* sQ = smem + 9702;     // 98*20
  float* sK = sQ + 1960;
  float* sV = sK + 1960;
  int tid = threadIdx.x;
  int blk = blockIdx.x;
  int hd = blk & 3;
  int wi = blk >> 2;
  int b = wi >> 10, d0 = (wi >> 8) & 3, h0 = (wi >> 4) & 15, w0 = wi & 15;

  // phase 0: load window tokens (98 x 64) at stride 65
  for (int i = tid; i < 6272; i += 256) {
    int n = i >> 6, c = i & 63;
    int dz = n / 49, r = n - dz * 49, hy = r / 7, wx = r - hy * 7;
    long p = ((long)(b * 8 + d0 * 2 + dz) * 112 + (h0 * 7 + hy)) * 112 + (w0 * 7 + wx);
    sA[n * 65 + c] = h[p * 64 + c];
  }
  __syncthreads();
  // phase 1: qkv for this head's 48 columns (16 per part), weights from global
  for (int i = tid; i < 1176; i += 256) {
    int part = i / 392;
    int rr = i - part * 392;
    int n = rr >> 2, j4 = (rr & 3) << 2;
    int colbase = part * 64 + hd * 16 + j4;
    float4 a4 = *(const float4*)(qb + colbase);
    float a0 = a4.x, a1 = a4.y, a2 = a4.z, a3 = a4.w;
    const float* xr = &sA[n * 65];
    const float* wp = qw + colbase;
    for (int c = 0; c < 64; c++) {
      float xv = xr[c];
      float4 w4 = *(const float4*)(wp + c * 192);
      a0 += xv * w4.x;
      a1 += xv * w4.y;
      a2 += xv * w4.z;
      a3 += xv * w4.w;
    }
    float* dst = part == 0 ? sQ : (part == 1 ? sK : sV);
    float sc = part == 0 ? 0.25f : 1.0f;
    float* dp = dst + n * 20 + j4;
    *(float4*)dp = make_float4(a0 * sc, a1 * sc, a2 * sc, a3 * sc);
  }
  __syncthreads();
  // phase 2: scores + relative position bias (scores at stride 99 over sA)
  for (int i = tid; i < 2450; i += 256) {
    int n = i / 25, mc = i - n * 25;
    int m0 = mc * 4;
    float4 q0 = *(float4*)&sQ[n * 20], q1 = *(float4*)&sQ[n * 20 + 4];
    float4 q2 = *(float4*)&sQ[n * 20 + 8], q3 = *(float4*)&sQ[n * 20 + 12];
    int dzn = n / 49, rn = n - dzn * 49, hyn = rn / 7, wxn = rn - hyn * 7;
    int mend = (m0 + 4 > 98) ? 98 : m0 + 4;
    for (int m = m0; m < mend; m++) {
      float4 k0 = *(float4*)&sK[m * 20], k1 = *(float4*)&sK[m * 20 + 4];
      float4 k2 = *(float4*)&sK[m * 20 + 8], k3 = *(float4*)&sK[m * 20 + 12];
      float sv = q0.x * k0.x + q0.y * k0.y + q0.z * k0.z + q0.w * k0.w
               + q1.x * k1.x + q1.y * k1.y + q1.z * k1.z + q1.w * k1.w
               + q2.x * k2.x + q2.y * k2.y + q2.z * k2.z + q2.w * k2.w
               + q3.x * k3.x + q3.y * k3.y + q3.z * k3.z + q3.w * k3.w;
      int dzm = m / 49, rm = m - dzm * 49, hym = rm / 7, wxm = rm - hym * 7;
      int idx = (dzn - dzm + 1) * 169 + (hyn - hym + 6) * 13 + (wxn - wxm + 6);
      sA[n * 99 + m] = sv + rpb[idx * 4 + hd];
    }
  }
  __syncthreads();
  // phase 3: softmax per row (stride 99 -> conflict-free across lanes)
  if (tid < 98) {
    float* row = &sA[tid * 99];
    float mx = -1e30f;
    for (int m = 0; m < 98; m++) mx = fmaxf(mx, row[m]);
    float sum = 0.f;
    for (int m = 0; m < 98; m++) { float e = __expf(row[m] - mx); row[m] = e; sum += e; }
    float inv = 1.f / sum;
    for (int m = 0; m < 98; m++) row[m] *= inv;
  }
  __syncthreads();
  // phase 4: P @ V -> attn out (pre-projection), layout (window, n, 64)
  for (int i = tid; i < 392; i += 256) {
    int n = i >> 2, e0 = (i & 3) << 2;
    float a0 = 0, a1 = 0, a2 = 0, a3 = 0;
    const float* prow = &sA[n * 99];
    for (int m = 0; m < 98; m++) {
      float p = prow[m];
      float4 vv = *(float4*)&sV[m * 20 + e0];
      a0 += p * vv.x; a1 += p * vv.y; a2 += p * vv.z; a3 += p * vv.w;
    }
    long ob = ((long)wi * 98 + n) * 64 + hd * 16 + e0;
    aout[ob] = a0; aout[ob + 1] = a1; aout[ob + 2] = a2; aout[ob + 3] = a3;
  }
}

// ---------------- Spatial projection: (nw*98,64)@(64,64) scatter-add into acc ---
__global__ __launch_bounds__(256) void k_sproj(const float* __restrict__ ain, const float* __restrict__ pw,
    const float* __restrict__ pb, float* __restrict__ acc) {
  __shared__ float srow[4][64];
  int wv = threadIdx.x >> 6, c = threadIdx.x & 63;
  int row = blockIdx.x * 4 + wv;
  srow[wv][c] = ain[(long)row * 64 + c];
  __syncthreads();
  float a = pb[c];
  const float* xr = srow[wv];
  const float* wp = pw + c;
  for (int k = 0; k < 64; k++) a += xr[k] * wp[k * 64];
  int wi = row / 98, n = row - wi * 98;
  int b = wi >> 10, d0 = (wi >> 8) & 3, h0 = (wi >> 4) & 15, w0 = wi & 15;
  int dz = n / 49, r2 = n - dz * 49, hy = r2 / 7, wx = r2 - hy * 7;
  long p = ((long)(b * 8 + d0 * 2 + dz) * 112 + (h0 * 7 + hy)) * 112 + (w0 * 7 + wx);
  acc[p * 64 + c] += a;
}

// ---------------- Temporal attention: one wave per pixel sequence (D=8) ---------
// LDS per wave: xt 8x65=520 | qkv 8x97=776 | sp 64 | o 8x33=264  => 1624 floats
__global__ __launch_bounds__(256) void k_tattn(const float* __restrict__ h, const float* __restrict__ qw,
    const float* __restrict__ qb, const float* __restrict__ rpbt, const float* __restrict__ pw,
    const float* __restrict__ pb, float* __restrict__ acc) {
  __shared__ float sm[4][1624];
  int wv = threadIdx.x >> 6, lane = threadIdx.x & 63;
  int s = blockIdx.x * 4 + wv;
  int b = s / 12544, rr = s - b * 12544, hy = rr / 112, wx = rr - hy * 112;
  float* xt = sm[wv];       // 8 x stride 65
  float* qkv = xt + 520;    // 8 x stride 97
  float* sp = qkv + 776;    // 64
  float* o = sp + 64;       // 8 x stride 33
  long pbase = ((long)b * 896 + hy) * 112 + wx;   // pos of token n = pbase + n*12544
  for (int i = lane; i < 512; i += 64) {
    int n = i >> 6, c = i & 63;
    xt[n * 65 + c] = h[(pbase + (long)n * 12544) * 64 + c];
  }
  __syncthreads();
  // qkv (8 x 96)
  for (int i = lane; i < 192; i += 64) {
    int n = i / 24, c4 = (i - n * 24) * 4;
    float4 a4 = *(const float4*)(qb + c4);
    float a0 = a4.x, a1 = a4.y, a2 = a4.z, a3 = a4.w;
    const float* xr = &xt[n * 65];
    const float* wp = qw + c4;
    for (int c = 0; c < 64; c++) {
      float xv = xr[c];
      float4 w4 = *(const float4*)(wp + c * 96);
      a0 += xv * w4.x; a1 += xv * w4.y;
      a2 += xv * w4.z; a3 += xv * w4.w;
    }
    float sc = (c4 < 32) ? 0.25f : 1.f;
    int ob = n * 97 + c4;
    qkv[ob] = a0 * sc; qkv[ob + 1] = a1 * sc; qkv[ob + 2] = a2 * sc; qkv[ob + 3] = a3 * sc;
  }
  __syncthreads();
  int n8 = lane >> 3, m8 = lane & 7;
  for (int hd = 0; hd < 4; hd++) {
    float sc = 0.f;
    const float* qr = &qkv[n8 * 97 + hd * 8];
    const float* kr = &qkv[m8 * 97 + 32 + hd * 8];
#pragma unroll
    for (int e = 0; e < 8; e++) sc += qr[e] * kr[e];
    sc += rpbt[(n8 - m8 + 7) * 4 + hd];
    sp[lane] = sc;
    __syncthreads();
    if (lane < 8) {
      float* row = &sp[lane * 8];
      float mx = -1e30f;
      for (int m = 0; m < 8; m++) mx = fmaxf(mx, row[m]);
      float sum = 0.f;
      for (int m = 0; m < 8; m++) { float e = __expf(row[m] - mx); row[m] = e; sum += e; }
      float inv = 1.f / sum;
      for (int m = 0; m < 8; m++) row[m] *= inv;
    }
    __syncthreads();
    float a = 0.f;
    const float* prow = &sp[n8 * 8];
#pragma unroll
    for (int m = 0; m < 8; m++) a += prow[m] * qkv[m * 97 + 64 + hd * 8 + m8];
    o[n8 * 33 + hd * 8 + m8] = a;
    __syncthreads();
  }
  // projection (32 -> 64), add into acc
  for (int i = lane; i < 128; i += 64) {
    int n = i >> 4, c4 = (i & 15) << 2;
    float4 a4 = *(const float4*)(pb + c4);
    float a0 = a4.x, a1 = a4.y, a2 = a4.z, a3 = a4.w;
    const float* orow = &o[n * 33];
    const float* wp = pw + c4;
    for (int k = 0; k < 32; k++) {
      float ov = orow[k];
      float4 w4 = *(const float4*)(wp + k * 64);
      a0 += ov * w4.x; a1 += ov * w4.y; a2 += ov * w4.z; a3 += ov * w4.w;
    }
    long ab = (pbase + (long)n * 12544) * 64 + c4;
    acc[ab] += a0; acc[ab + 1] += a1; acc[ab + 2] += a2; acc[ab + 3] += a3;
  }
}

// ---------------- Direct 3x3x3 conv, channels-last, 32ci -> 32co ----------------
// grid (2, 112, 16=b*8+d); block 256 = 8 w-groups x 32 co; each thread 8 outputs
__global__ __launch_bounds__(256) void k_conv(const float* __restrict__ in, int ics,
    const float* __restrict__ wgt, const float* __restrict__ bias,
    const float* __restrict__ addsrc, int acs, float* __restrict__ out, int lrelu) {
  __shared__ __align__(16) float s_in[32 * 68];
  __shared__ float s_w[32 * 97];
  int tid = threadIdx.x;
  int co = tid & 31, ws8 = tid >> 5;
  int wtile = blockIdx.x, hh = blockIdx.y, bz = blockIdx.z;
  int d = bz & 7, bb = bz >> 3;
  int wbase = wtile * 64;
  float acc[8];
#pragma unroll
  for (int q = 0; q < 8; q++) acc[q] = 0.f;
  for (int kd = 0; kd < 3; kd++) {
    int zd = d + kd - 1;
    if (zd < 0 || zd > 7) continue;
    for (int kh = 0; kh < 3; kh++) {
      int yy = hh + kh - 1;
      if (yy < 0 || yy > 111) continue;
      __syncthreads();
      int prow = ((bb * 8 + zd) * 112 + yy) * 112;
      for (int i = tid; i < 2112; i += 256) {
        int ci = i & 31, j = i >> 5;
        int w = wbase - 1 + j;
        float v = 0.f;
        if (w >= 0 && w < 112) v = in[(long)(prow + w) * ics + ci];
        s_in[ci * 68 + j] = v;
      }
      for (int i = tid; i < 3072; i += 256) {
        int c2 = i / 96, r = i - c2 * 96;
        int ci = r / 3, kw = r - ci * 3;
        s_w[c2 * 97 + r] = wgt[(c2 * 32 + ci) * 27 + kd * 9 + kh * 3 + kw];
      }
      __syncthreads();
      int jb = ws8 * 8;
      for (int ci = 0; ci < 32; ci++) {
        const float* ip = &s_in[ci * 68 + jb];
        float4 A = *(const float4*)ip;
        float4 Bv = *(const float4*)(ip + 4);
        float2 Cv = *(const float2*)(ip + 8);
        float v[10] = {A.x, A.y, A.z, A.w, Bv.x, Bv.y, Bv.z, Bv.w, Cv.x, Cv.y};
        const float* wr = &s_w[co * 97 + ci * 3];
        float w0 = wr[0], w1 = wr[1], w2 = wr[2];
#pragma unroll
        for (int q = 0; q < 8; q++)
          acc[q] += v[q] * w0 + v[q + 1] * w1 + v[q + 2] * w2;
      }
    }
  }
  float bv = bias[co];
  int w00 = wbase + ws8 * 8;
  int pcol = (bz * 112 + hh) * 112;
#pragma unroll
  for (int q = 0; q < 8; q++) {
    int w = w00 + q;
    if (w < 112) {
      float vv = acc[q] + bv;
      if (lrelu) vv = vv > 0.f ? vv : 0.01f * vv;
      long pos = pcol + w;
      if (addsrc) vv += addsrc[pos * acs + co];
      out[pos * 32 + co] = vv;
    }
  }
}

// ---------------- x2 += y1 (in place in h2's channel 32..63) --------------------
__global__ __launch_bounds__(256) void k_addx2(float* __restrict__ h2, const float* __restrict__ y1) {
  long i = (long)blockIdx.x * 256 + threadIdx.x;
  long pos = i >> 5;
  int c = (int)(i & 31);
  h2[pos * 64 + 32 + c] += y1[i];
}

// ---------------- out = acc + concat(y1,y2) -------------------------------------
__global__ __launch_bounds__(256) void k_final(const float* __restrict__ acc, const float* __restrict__ y1,
    const float* __restrict__ y2, float* __restrict__ out) {
  long i = (long)blockIdx.x * 256 + threadIdx.x;
  long pos = i >> 6;
  int c = (int)(i & 63);
  float v = acc[i] + (c < 32 ? y1[pos * 32 + c] : y2[pos * 32 + c - 32]);
  out[i] = v;
}

extern "C" void kernel_launch(void* const* d_in, const int* in_sizes, int n_in,
                              void* d_out, int out_size, void* d_ws, size_t ws_size,
                              hipStream_t stream) {
  const float* x        = (const float*)d_in[0];
  // d_in[1] mask_matrix: unused (all zeros in reference path)
  const float* g1       = (const float*)d_in[2];
  const float* b1       = (const float*)d_in[3];
  const float* rpb_s    = (const float*)d_in[4];
  const float* qkv_w_s  = (const float*)d_in[5];
  const float* qkv_b_s  = (const float*)d_in[6];
  const float* proj_w_s = (const float*)d_in[7];
  const float* proj_b_s = (const float*)d_in[8];
  const float* rpb_t    = (const float*)d_in[9];
  const float* qkv_w_t  = (const float*)d_in[10];
  const float* qkv_b_t  = (const float*)d_in[11];
  const float* proj_w_t = (const float*)d_in[12];
  const float* proj_b_t = (const float*)d_in[13];
  const float* g2       = (const float*)d_in[14];
  const float* b2       = (const float*)d_in[15];
  const float* c1w = (const float*)d_in[16];
  const float* c1b = (const float*)d_in[17];
  const float* c2w = (const float*)d_in[18];
  const float* c2b = (const float*)d_in[19];
  const float* c3w = (const float*)d_in[20];
  const float* c3b = (const float*)d_in[21];
  const float* c4w = (const float*)d_in[22];
  const float* c4b = (const float*)d_in[23];

  // workspace layout (fp32): acc | hbuf(h/h2) | tbuf | y1 | y2  = ~180 MB
  float* acc  = (float*)d_ws;
  float* hbuf = acc + 12845056;
  float* tbuf = hbuf + 12845056;
  float* y1   = tbuf + 6422528;
  float* y2   = y1 + 6422528;
  float* aout = tbuf;  // spans tbuf..y1 (12.85M floats), dead before convs start

  // 1. LN1: h = LN(x); acc = x
  k_ln<<<50176, 256, 0, stream>>>(x, g1, b1, hbuf, acc);
  // 2. spatial window attention (qkv + softmax + PV) -> aout
  k_sattn<<<8192, 256, 0, stream>>>(hbuf, qkv_w_s, qkv_b_s, rpb_s, aout);
  // 3. spatial projection, scatter-add into acc
  k_sproj<<<50176, 256, 0, stream>>>(aout, proj_w_s, proj_b_s, acc);
  // 4. temporal attention, add into acc
  k_tattn<<<6272, 256, 0, stream>>>(hbuf, qkv_w_t, qkv_b_t, rpb_t, proj_w_t, proj_b_t, acc);
  // 5. LN2: h2 = LN(acc)   (channels-last kept; reference transpose is layout-only)
  k_ln<<<50176, 256, 0, stream>>>(acc, g2, b2, hbuf, nullptr);
  // 6. conv path 1: t = lrelu(conv(x1)); y1 = x1 + conv(t)
  k_conv<<<dim3(2, 112, 16), 256, 0, stream>>>(hbuf, 64, c1w, c1b, nullptr, 0, tbuf, 1);
  k_conv<<<dim3(2, 112, 16), 256, 0, stream>>>(tbuf, 32, c2w, c2b, hbuf, 64, y1, 0);
  // 7. x2 += y1 (in place)
  k_addx2<<<25088, 256, 0, stream>>>(hbuf, y1);
  // 8. conv path 2: t = lrelu(conv(x2b)); y2 = x2b + conv(t)
  k_conv<<<dim3(2, 112, 16), 256, 0, stream>>>(hbuf + 32, 64, c3w, c3b, nullptr, 0, tbuf, 1);
  k_conv<<<dim3(2, 112, 16), 256, 0, stream>>>(tbuf, 32, c4w, c4b, hbuf + 32, 64, y2, 0);
  // 9. out = acc + concat(y1, y2)
  k_final<<<50176, 256, 0, stream>>>(acc, y1, y2, (float*)d_out);
}

// Round 5
// 3217.503 us; speedup vs baseline: 1.4272x; 1.1346x over previous
//
#include <hip/hip_runtime.h>
#include <hip/hip_bf16.h>

typedef unsigned short u16;
typedef unsigned int u32;

__device__ __forceinline__ u16 f2b(float v) {
  u32 bits = __float_as_uint(v);
  bits += 0x7fffu + ((bits >> 16) & 1u);
  return (u16)(bits >> 16);
}
__device__ __forceinline__ float b2f(u16 u) { return __uint_as_float(((u32)u) << 16); }

// ---------------- LayerNorm (f32 in) : writes h (f32) and optionally acc = x ----
__global__ __launch_bounds__(256) void k_ln(const float* __restrict__ x, const float* __restrict__ g,
    const float* __restrict__ b, float* __restrict__ hout, float* __restrict__ acc) {
  int token = blockIdx.x * 4 + (threadIdx.x >> 6);
  int lane = threadIdx.x & 63;
  long base = (long)token * 64 + lane;
  float v = x[base];
  float s = v;
#pragma unroll
  for (int o = 32; o; o >>= 1) s += __shfl_xor(s, o);
  float m = s * 0.015625f;
  float d = v - m;
  float q = d * d;
#pragma unroll
  for (int o = 32; o; o >>= 1) q += __shfl_xor(q, o);
  float r = rsqrtf(q * 0.015625f + 1e-5f);
  hout[base] = d * r * g[lane] + b[lane];
  if (acc) acc[base] = v;
}

// ---------------- Spatial qkv: dense GEMM, h read once, bf16 windowed output ----
// grid 6272 x 256; wave handles 8 tokens x 64 lanes; lane owns cols {l, l+64, l+128}
__global__ __launch_bounds__(256) void k_qkvs(const float* __restrict__ h, const float* __restrict__ qw,
    const float* __restrict__ qb, u16* __restrict__ Qg, u16* __restrict__ Kg, u16* __restrict__ Vg) {
  int wv = threadIdx.x >> 6, lane = threadIdx.x & 63;
  long t0 = (long)blockIdx.x * 32 + wv * 8;
  float aq[8], ak[8], av[8];
  float bq = qb[lane], bk = qb[64 + lane], bv = qb[128 + lane];
#pragma unroll
  for (int i = 0; i < 8; i++) { aq[i] = bq; ak[i] = bk; av[i] = bv; }
  for (int k = 0; k < 64; k++) {
    float wq = qw[k * 192 + lane];
    float wk = qw[k * 192 + 64 + lane];
    float wvv = qw[k * 192 + 128 + lane];
#pragma unroll
    for (int i = 0; i < 8; i++) {
      float xv = h[(t0 + i) * 64 + k];   // wave-uniform -> scalar load
      aq[i] += xv * wq; ak[i] += xv * wk; av[i] += xv * wvv;
    }
  }
  int hd = lane >> 4, j = lane & 15;
#pragma unroll
  for (int i = 0; i < 8; i++) {
    long p = t0 + i;
    int b = (int)(p / 100352); int r = (int)(p - (long)b * 100352);
    int d = r / 12544; int r2 = r - d * 12544;
    int hy = r2 / 112, wx = r2 - hy * 112;
    int d0 = d >> 1, dz = d & 1, h0 = hy / 7, oy = hy - h0 * 7, w0 = wx / 7, ox = wx - w0 * 7;
    int wi = ((b * 4 + d0) * 16 + h0) * 16 + w0;
    int n = dz * 49 + oy * 7 + ox;
    long o = (long)(wi * 4 + hd) * 1568 + n * 16 + j;
    Qg[o] = f2b(aq[i] * 0.25f);
    Kg[o] = f2b(ak[i]);
    Vg[o] = f2b(av[i]);
  }
}

// ---------------- Spatial attention + fused projection: one block per window ----
// heads looped; scores in 49-row halves (fp32); proj accumulated in registers;
// writes acc[p*64+c] += proj + bias directly (k_sproj eliminated).
__global__ __launch_bounds__(256) void k_sattn2(const u16* __restrict__ Qg, const u16* __restrict__ Kg,
    const u16* __restrict__ Vg, const float* __restrict__ rpb, const float* __restrict__ pw,
    const float* __restrict__ pb, float* __restrict__ accg) {
  __shared__ __align__(16) float sQ[98 * 20];
  __shared__ __align__(16) float sK[98 * 20];
  __shared__ __align__(16) float sV[98 * 20];
  __shared__ __align__(16) float sS[49 * 99];
  __shared__ __align__(16) float sPV[49 * 20];
  __shared__ int sT[98];
  int tid = threadIdx.x;
  int wi = blockIdx.x;
  if (tid < 98) {
    int dz = tid / 49, r = tid - dz * 49, hy = r / 7, wx = r - hy * 7;
    sT[tid] = dz * 169 + hy * 13 + wx;
  }
  float pacc[4][8];
#pragma unroll
  for (int k = 0; k < 4; k++)
#pragma unroll
    for (int e = 0; e < 8; e++) pacc[k][e] = 0.f;

  for (int hd = 0; hd < 4; hd++) {
    long base = (long)(wi * 4 + hd) * 1568;
    __syncthreads();   // protect sQ/K/V from previous iteration's readers
    for (int i = tid; i < 1568; i += 256) { int n = i >> 4, j = i & 15; sQ[n * 20 + j] = b2f(Qg[base + i]); }
    for (int i = tid; i < 1568; i += 256) { int n = i >> 4, j = i & 15; sK[n * 20 + j] = b2f(Kg[base + i]); }
    for (int i = tid; i < 1568; i += 256) { int n = i >> 4, j = i & 15; sV[n * 20 + j] = b2f(Vg[base + i]); }
    __syncthreads();
    for (int half = 0; half < 2; half++) {
      // scores for rows [half*49, half*49+49)
      for (int it = tid; it < 1225; it += 256) {
        int nn = it / 25, mc = it - nn * 25;
        int n = half * 49 + nn, m0 = mc * 4;
        const float* qr = &sQ[n * 20];
        float4 q0 = *(float4*)qr, q1 = *(float4*)(qr + 4);
        float4 q2 = *(float4*)(qr + 8), q3 = *(float4*)(qr + 12);
        int tn = sT[n] + 253;
        int mend = (m0 + 4 > 98) ? 98 : m0 + 4;
        for (int m = m0; m < mend; m++) {
          const float* kr = &sK[m * 20];
          float4 k0 = *(float4*)kr, k1 = *(float4*)(kr + 4);
          float4 k2 = *(float4*)(kr + 8), k3 = *(float4*)(kr + 12);
          float sv = q0.x * k0.x + q0.y * k0.y + q0.z * k0.z + q0.w * k0.w
                   + q1.x * k1.x + q1.y * k1.y + q1.z * k1.z + q1.w * k1.w
                   + q2.x * k2.x + q2.y * k2.y + q2.z * k2.z + q2.w * k2.w
                   + q3.x * k3.x + q3.y * k3.y + q3.z * k3.z + q3.w * k3.w;
          int idx = tn - sT[m];
          sS[nn * 99 + m] = sv + rpb[idx * 4 + hd];
        }
      }
      __syncthreads();
      if (tid < 49) {
        float* row = &sS[tid * 99];
        float mx = -1e30f;
        for (int m = 0; m < 98; m++) mx = fmaxf(mx, row[m]);
        float sum = 0.f;
        for (int m = 0; m < 98; m++) { float e = __expf(row[m] - mx); row[m] = e; sum += e; }
        float inv = 1.f / sum;
        for (int m = 0; m < 98; m++) row[m] *= inv;
      }
      __syncthreads();
      // PV: 49 rows x 16 cols
      if (tid < 196) {
        int nn = tid >> 2, e0 = (tid & 3) << 2;
        float a0 = 0, a1 = 0, a2 = 0, a3 = 0;
        const float* prow = &sS[nn * 99];
        for (int m = 0; m < 98; m++) {
          float p = prow[m];
          const float* vr = &sV[m * 20 + e0];
          float4 vv = *(float4*)vr;
          a0 += p * vv.x; a1 += p * vv.y; a2 += p * vv.z; a3 += p * vv.w;
        }
        *(float4*)&sPV[nn * 20 + e0] = make_float4(a0, a1, a2, a3);
      }
      __syncthreads();
      // fused projection: pacc[n][c8*8..] += PV[n][j] * Wp[hd*16+j][c]
#pragma unroll
      for (int k = 0; k < 4; k++) {
        int u = k * 256 + tid;
        if (u < 784) {
          int n = u >> 3, c8 = u & 7;
          if (n >= half * 49 && n < half * 49 + 49) {
            int nn = n - half * 49;
            const float* wrow = pw + hd * 16 * 64 + c8 * 8;
            for (int j = 0; j < 16; j++) {
              float pv = sPV[nn * 20 + j];
              float4 w0 = *(const float4*)(wrow + j * 64);
              float4 w1 = *(const float4*)(wrow + j * 64 + 4);
              pacc[k][0] += pv * w0.x; pacc[k][1] += pv * w0.y;
              pacc[k][2] += pv * w0.z; pacc[k][3] += pv * w0.w;
              pacc[k][4] += pv * w1.x; pacc[k][5] += pv * w1.y;
              pacc[k][6] += pv * w1.z; pacc[k][7] += pv * w1.w;
            }
          }
        }
      }
      __syncthreads();
    }
  }
  // write: acc[p*64 + c] += pacc + bias
  int b = wi >> 10, d0 = (wi >> 8) & 3, h0 = (wi >> 4) & 15, w0 = wi & 15;
#pragma unroll
  for (int k = 0; k < 4; k++) {
    int u = k * 256 + tid;
    if (u < 784) {
      int n = u >> 3, c8 = u & 7;
      int dz = n / 49, r = n - dz * 49, oy = r / 7, ox = r - oy * 7;
      long p = ((long)(b * 8 + d0 * 2 + dz) * 112 + (h0 * 7 + oy)) * 112 + (w0 * 7 + ox);
      float* ap = accg + p * 64 + c8 * 8;
      float4 x0 = *(float4*)ap, x1 = *(float4*)(ap + 4);
      float4 pb0 = *(const float4*)(pb + c8 * 8), pb1 = *(const float4*)(pb + c8 * 8 + 4);
      x0.x += pacc[k][0] + pb0.x; x0.y += pacc[k][1] + pb0.y;
      x0.z += pacc[k][2] + pb0.z; x0.w += pacc[k][3] + pb0.w;
      x1.x += pacc[k][4] + pb1.x; x1.y += pacc[k][5] + pb1.y;
      x1.z += pacc[k][6] + pb1.z; x1.w += pacc[k][7] + pb1.w;
      *(float4*)ap = x0; *(float4*)(ap + 4) = x1;
    }
  }
}

// ---------------- Temporal attention: one wave per pixel sequence (D=8) ---------
__global__ __launch_bounds__(256) void k_tattn(const float* __restrict__ h, const float* __restrict__ qw,
    const float* __restrict__ qb, const float* __restrict__ rpbt, const float* __restrict__ pw,
    const float* __restrict__ pb, float* __restrict__ acc) {
  __shared__ float sm[4][1624];
  int wv = threadIdx.x >> 6, lane = threadIdx.x & 63;
  int s = blockIdx.x * 4 + wv;
  int b = s / 12544, rr = s - b * 12544, hy = rr / 112, wx = rr - hy * 112;
  float* xt = sm[wv];       // 8 x stride 65
  float* qkv = xt + 520;    // 8 x stride 97
  float* sp = qkv + 776;    // 64
  float* o = sp + 64;       // 8 x stride 33
  long pbase = ((long)b * 896 + hy) * 112 + wx;   // pos of token n = pbase + n*12544
  for (int i = lane; i < 512; i += 64) {
    int n = i >> 6, c = i & 63;
    xt[n * 65 + c] = h[(pbase + (long)n * 12544) * 64 + c];
  }
  __syncthreads();
  // qkv (8 x 96)
  for (int i = lane; i < 192; i += 64) {
    int n = i / 24, c4 = (i - n * 24) * 4;
    float4 a4 = *(const float4*)(qb + c4);
    float a0 = a4.x, a1 = a4.y, a2 = a4.z, a3 = a4.w;
    const float* xr = &xt[n * 65];
    const float* wp = qw + c4;
    for (int c = 0; c < 64; c++) {
      float xv = xr[c];
      float4 w4 = *(const float4*)(wp + c * 96);
      a0 += xv * w4.x; a1 += xv * w4.y;
      a2 += xv * w4.z; a3 += xv * w4.w;
    }
    float sc = (c4 < 32) ? 0.25f : 1.f;
    int ob = n * 97 + c4;
    qkv[ob] = a0 * sc; qkv[ob + 1] = a1 * sc; qkv[ob + 2] = a2 * sc; qkv[ob + 3] = a3 * sc;
  }
  __syncthreads();
  int n8 = lane >> 3, m8 = lane & 7;
  for (int hd = 0; hd < 4; hd++) {
    float sc = 0.f;
    const float* qr = &qkv[n8 * 97 + hd * 8];
    const float* kr = &qkv[m8 * 97 + 32 + hd * 8];
#pragma unroll
    for (int e = 0; e < 8; e++) sc += qr[e] * kr[e];
    sc += rpbt[(n8 - m8 + 7) * 4 + hd];
    sp[lane] = sc;
    __syncthreads();
    if (lane < 8) {
      float* row = &sp[lane * 8];
      float mx = -1e30f;
      for (int m = 0; m < 8; m++) mx = fmaxf(mx, row[m]);
      float sum = 0.f;
      for (int m = 0; m < 8; m++) { float e = __expf(row[m] - mx); row[m] = e; sum += e; }
      float inv = 1.f / sum;
      for (int m = 0; m < 8; m++) row[m] *= inv;
    }
    __syncthreads();
    float a = 0.f;
    const float* prow = &sp[n8 * 8];
#pragma unroll
    for (int m = 0; m < 8; m++) a += prow[m] * qkv[m * 97 + 64 + hd * 8 + m8];
    o[n8 * 33 + hd * 8 + m8] = a;
    __syncthreads();
  }
  // projection (32 -> 64), add into acc
  for (int i = lane; i < 128; i += 64) {
    int n = i >> 4, c4 = (i & 15) << 2;
    float4 a4 = *(const float4*)(pb + c4);
    float a0 = a4.x, a1 = a4.y, a2 = a4.z, a3 = a4.w;
    const float* orow = &o[n * 33];
    const float* wp = pw + c4;
    for (int k = 0; k < 32; k++) {
      float ov = orow[k];
      float4 w4 = *(const float4*)(wp + k * 64);
      a0 += ov * w4.x; a1 += ov * w4.y; a2 += ov * w4.z; a3 += ov * w4.w;
    }
    long ab = (pbase + (long)n * 12544) * 64 + c4;
    acc[ab] += a0; acc[ab + 1] += a1; acc[ab + 2] += a2; acc[ab + 3] += a3;
  }
}

// ---------------- Direct 3x3x3 conv, channels-last, 32ci -> 32co ----------------
// grid (2, 112, 16=b*8+d); block 256 = 8 w-groups x 32 co; each thread 8 outputs
__global__ __launch_bounds__(256) void k_conv(const float* __restrict__ in, int ics,
    const float* __restrict__ wgt, const float* __restrict__ bias,
    const float* __restrict__ addsrc, int acs, float* __restrict__ out, int lrelu) {
  __shared__ __align__(16) float s_in[32 * 68];
  __shared__ float s_w[32 * 97];
  int tid = threadIdx.x;
  int co = tid & 31, ws8 = tid >> 5;
  int wtile = blockIdx.x, hh = blockIdx.y, bz = blockIdx.z;
  int d = bz & 7, bb = bz >> 3;
  int wbase = wtile * 64;
  float acc[8];
#pragma unroll
  for (int q = 0; q < 8; q++) acc[q] = 0.f;
  for (int kd = 0; kd < 3; kd++) {
    int zd = d + kd - 1;
    if (zd < 0 || zd > 7) continue;
    for (int kh = 0; kh < 3; kh++) {
      int yy = hh + kh - 1;
      if (yy < 0 || yy > 111) continue;
      __syncthreads();
      int prow = ((bb * 8 + zd) * 112 + yy) * 112;
      for (int i = tid; i < 2112; i += 256) {
        int ci = i & 31, j = i >> 5;
        int w = wbase - 1 + j;
        float v = 0.f;
        if (w >= 0 && w < 112) v = in[(long)(prow + w) * ics + ci];
        s_in[ci * 68 + j] = v;
      }
      for (int i = tid; i < 3072; i += 256) {
        int c2 = i / 96, r = i - c2 * 96;
        int ci = r / 3, kw = r - ci * 3;
        s_w[c2 * 97 + r] = wgt[(c2 * 32 + ci) * 27 + kd * 9 + kh * 3 + kw];
      }
      __syncthreads();
      int jb = ws8 * 8;
      for (int ci = 0; ci < 32; ci++) {
        const float* ip = &s_in[ci * 68 + jb];
        float4 A = *(const float4*)ip;
        float4 Bv = *(const float4*)(ip + 4);
        float2 Cv = *(const float2*)(ip + 8);
        float v[10] = {A.x, A.y, A.z, A.w, Bv.x, Bv.y, Bv.z, Bv.w, Cv.x, Cv.y};
        const float* wr = &s_w[co * 97 + ci * 3];
        float w0 = wr[0], w1 = wr[1], w2 = wr[2];
#pragma unroll
        for (int q = 0; q < 8; q++)
          acc[q] += v[q] * w0 + v[q + 1] * w1 + v[q + 2] * w2;
      }
    }
  }
  float bv = bias[co];
  int w00 = wbase + ws8 * 8;
  int pcol = (bz * 112 + hh) * 112;
#pragma unroll
  for (int q = 0; q < 8; q++) {
    int w = w00 + q;
    if (w < 112) {
      float vv = acc[q] + bv;
      if (lrelu) vv = vv > 0.f ? vv : 0.01f * vv;
      long pos = pcol + w;
      if (addsrc) vv += addsrc[pos * acs + co];
      out[pos * 32 + co] = vv;
    }
  }
}

// ---------------- x2 += y1 (in place in h2's channel 32..63) --------------------
__global__ __launch_bounds__(256) void k_addx2(float* __restrict__ h2, const float* __restrict__ y1) {
  long i = (long)blockIdx.x * 256 + threadIdx.x;
  long pos = i >> 5;
  int c = (int)(i & 31);
  h2[pos * 64 + 32 + c] += y1[i];
}

// ---------------- out = acc + concat(y1,y2) -------------------------------------
__global__ __launch_bounds__(256) void k_final(const float* __restrict__ acc, const float* __restrict__ y1,
    const float* __restrict__ y2, float* __restrict__ out) {
  long i = (long)blockIdx.x * 256 + threadIdx.x;
  long pos = i >> 6;
  int c = (int)(i & 63);
  float v = acc[i] + (c < 32 ? y1[pos * 32 + c] : y2[pos * 32 + c - 32]);
  out[i] = v;
}

extern "C" void kernel_launch(void* const* d_in, const int* in_sizes, int n_in,
                              void* d_out, int out_size, void* d_ws, size_t ws_size,
                              hipStream_t stream) {
  const float* x        = (const float*)d_in[0];
  // d_in[1] mask_matrix: unused (all zeros in reference path)
  const float* g1       = (const float*)d_in[2];
  const float* b1       = (const float*)d_in[3];
  const float* rpb_s    = (const float*)d_in[4];
  const float* qkv_w_s  = (const float*)d_in[5];
  const float* qkv_b_s  = (const float*)d_in[6];
  const float* proj_w_s = (const float*)d_in[7];
  const float* proj_b_s = (const float*)d_in[8];
  const float* rpb_t    = (const float*)d_in[9];
  const float* qkv_w_t  = (const float*)d_in[10];
  const float* qkv_b_t  = (const float*)d_in[11];
  const float* proj_w_t = (const float*)d_in[12];
  const float* proj_b_t = (const float*)d_in[13];
  const float* g2       = (const float*)d_in[14];
  const float* b2       = (const float*)d_in[15];
  const float* c1w = (const float*)d_in[16];
  const float* c1b = (const float*)d_in[17];
  const float* c2w = (const float*)d_in[18];
  const float* c2b = (const float*)d_in[19];
  const float* c3w = (const float*)d_in[20];
  const float* c3b = (const float*)d_in[21];
  const float* c4w = (const float*)d_in[22];
  const float* c4b = (const float*)d_in[23];

  // workspace (fp32 elems): acc(12.8M) | hbuf(12.8M) | C region (19.3M floats)
  // C region: first QKV bf16 (3 x 12.8M u16 = exact fit), later tbuf/y1/y2 for convs
  float* acc  = (float*)d_ws;
  float* hbuf = acc + 12845056;
  float* creg = hbuf + 12845056;
  u16* Qg = (u16*)creg;
  u16* Kg = Qg + 12845056;
  u16* Vg = Kg + 12845056;
  float* tbuf = creg;
  float* y1   = creg + 6422528;
  float* y2   = y1 + 6422528;

  // 1. LN1: h = LN(x); acc = x
  k_ln<<<50176, 256, 0, stream>>>(x, g1, b1, hbuf, acc);
  // 2. spatial qkv (dense GEMM) -> bf16 windowed Q/K/V
  k_qkvs<<<6272, 256, 0, stream>>>(hbuf, qkv_w_s, qkv_b_s, Qg, Kg, Vg);
  // 3. spatial attention + fused projection, acc += (one block per window)
  k_sattn2<<<2048, 256, 0, stream>>>(Qg, Kg, Vg, rpb_s, proj_w_s, proj_b_s, acc);
  // 4. temporal attention, add into acc
  k_tattn<<<6272, 256, 0, stream>>>(hbuf, qkv_w_t, qkv_b_t, rpb_t, proj_w_t, proj_b_t, acc);
  // 5. LN2: h2 = LN(acc)
  k_ln<<<50176, 256, 0, stream>>>(acc, g2, b2, hbuf, nullptr);
  // 6. conv path 1: t = lrelu(conv(x1)); y1 = x1 + conv(t)
  k_conv<<<dim3(2, 112, 16), 256, 0, stream>>>(hbuf, 64, c1w, c1b, nullptr, 0, tbuf, 1);
  k_conv<<<dim3(2, 112, 16), 256, 0, stream>>>(tbuf, 32, c2w, c2b, hbuf, 64, y1, 0);
  // 7. x2 += y1 (in place)
  k_addx2<<<25088, 256, 0, stream>>>(hbuf, y1);
  // 8. conv path 2: t = lrelu(conv(x2b)); y2 = x2b + conv(t)
  k_conv<<<dim3(2, 112, 16), 256, 0, stream>>>(hbuf + 32, 64, c3w, c3b, nullptr, 0, tbuf, 1);
  k_conv<<<dim3(2, 112, 16), 256, 0, stream>>>(tbuf, 32, c4w, c4b, hbuf + 32, 64, y2, 0);
  // 9. out = acc + concat(y1, y2)
  k_final<<<50176, 256, 0, stream>>>(acc, y1, y2, (float*)d_out);
}

// Round 6
// 2518.523 us; speedup vs baseline: 1.8233x; 1.2775x over previous
//
#include <hip/hip_runtime.h>
#include <hip/hip_bf16.h>

typedef unsigned short u16;
typedef unsigned int u32;

__device__ __forceinline__ u16 f2b(float v) {
  u32 bits = __float_as_uint(v);
  bits += 0x7fffu + ((bits >> 16) & 1u);
  return (u16)(bits >> 16);
}
__device__ __forceinline__ float b2f(u16 u) { return __uint_as_float(((u32)u) << 16); }

// ---------------- LayerNorm (f32 in) : writes h (f32) and optionally acc = x ----
__global__ __launch_bounds__(256) void k_ln(const float* __restrict__ x, const float* __restrict__ g,
    const float* __restrict__ b, float* __restrict__ hout, float* __restrict__ acc) {
  int token = blockIdx.x * 4 + (threadIdx.x >> 6);
  int lane = threadIdx.x & 63;
  long base = (long)token * 64 + lane;
  float v = x[base];
  float s = v;
#pragma unroll
  for (int o = 32; o; o >>= 1) s += __shfl_xor(s, o);
  float m = s * 0.015625f;
  float d = v - m;
  float q = d * d;
#pragma unroll
  for (int o = 32; o; o >>= 1) q += __shfl_xor(q, o);
  float r = rsqrtf(q * 0.015625f + 1e-5f);
  hout[base] = d * r * g[lane] + b[lane];
  if (acc) acc[base] = v;
}

// ---------------- Spatial qkv: dense GEMM, h read once, bf16 windowed output ----
// wave handles 8 tokens; token rows staged in LDS -> inner reads are broadcasts
__global__ __launch_bounds__(256) void k_qkvs(const float* __restrict__ h, const float* __restrict__ qw,
    const float* __restrict__ qb, u16* __restrict__ Qg, u16* __restrict__ Kg, u16* __restrict__ Vg) {
  __shared__ float sx[4][512];
  int wv = threadIdx.x >> 6, lane = threadIdx.x & 63;
  long t0 = (long)blockIdx.x * 32 + wv * 8;
  for (int i = lane; i < 512; i += 64) sx[wv][i] = h[t0 * 64 + i];
  __syncthreads();
  float aq[8], ak[8], av[8];
  float bq = qb[lane], bk = qb[64 + lane], bv = qb[128 + lane];
#pragma unroll
  for (int i = 0; i < 8; i++) { aq[i] = bq; ak[i] = bk; av[i] = bv; }
  for (int k = 0; k < 64; k++) {
    float wq = qw[k * 192 + lane];
    float wk = qw[k * 192 + 64 + lane];
    float wvv = qw[k * 192 + 128 + lane];
#pragma unroll
    for (int i = 0; i < 8; i++) {
      float xv = sx[wv][i * 64 + k];   // same addr across lanes -> broadcast
      aq[i] += xv * wq; ak[i] += xv * wk; av[i] += xv * wvv;
    }
  }
  int hd = lane >> 4, j = lane & 15;
#pragma unroll
  for (int i = 0; i < 8; i++) {
    long p = t0 + i;
    int b = (int)(p / 100352); int r = (int)(p - (long)b * 100352);
    int d = r / 12544; int r2 = r - d * 12544;
    int hy = r2 / 112, wx = r2 - hy * 112;
    int d0 = d >> 1, dz = d & 1, h0 = hy / 7, oy = hy - h0 * 7, w0 = wx / 7, ox = wx - w0 * 7;
    int wi = ((b * 4 + d0) * 16 + h0) * 16 + w0;
    int n = dz * 49 + oy * 7 + ox;
    long o = (long)(wi * 4 + hd) * 1568 + n * 16 + j;
    Qg[o] = f2b(aq[i] * 0.25f);
    Kg[o] = f2b(ak[i]);
    Vg[o] = f2b(av[i]);
  }
}

// ---------------- Spatial attention + fused projection: one block per window ----
// thread = n*2+mh owns Q-row n (regs) and m-half mh; scores p[49] in registers;
// in-register softmax (pair-combine via shfl); PV partials -> sPV; proj fused.
__global__ __launch_bounds__(256) void k_sattn2(const u16* __restrict__ Qg, const u16* __restrict__ Kg,
    const u16* __restrict__ Vg, const float* __restrict__ rpb, const float* __restrict__ pw,
    const float* __restrict__ pb, float* __restrict__ accg) {
  __shared__ __align__(16) float sQ[98 * 20];
  __shared__ __align__(16) float sK[98 * 20];
  __shared__ __align__(16) float sV[98 * 20];
  __shared__ __align__(16) float sPV[98 * 40];   // [n][mh*20 + e]
  __shared__ int sT[128];
  int tid = threadIdx.x;
  int wi = blockIdx.x;
  if (tid < 98) {
    int dz = tid / 49, r = tid - dz * 49, hy = r / 7, wx = r - hy * 7;
    sT[tid] = dz * 169 + hy * 13 + wx;
  } else if (tid < 128) sT[tid] = 0;
  int n = tid >> 1;
  int mh = tid & 1;
  bool act = tid < 196;
  float pacc[4][8];
#pragma unroll
  for (int k = 0; k < 4; k++)
#pragma unroll
    for (int e = 0; e < 8; e++) pacc[k][e] = 0.f;
  __syncthreads();
  int tn = sT[n] + 253;   // n<128 always in-bounds; only act lanes use it

  for (int hd = 0; hd < 4; hd++) {
    long base = (long)(wi * 4 + hd) * 1568;
    for (int i = tid; i < 1568; i += 256) { int r = i >> 4, j = i & 15; sQ[r * 20 + j] = b2f(Qg[base + i]); }
    for (int i = tid; i < 1568; i += 256) { int r = i >> 4, j = i & 15; sK[r * 20 + j] = b2f(Kg[base + i]); }
    for (int i = tid; i < 1568; i += 256) { int r = i >> 4, j = i & 15; sV[r * 20 + j] = b2f(Vg[base + i]); }
    __syncthreads();
    if (act) {
      const float* qr = &sQ[n * 20];
      float4 Q0 = *(const float4*)qr, Q1 = *(const float4*)(qr + 4);
      float4 Q2 = *(const float4*)(qr + 8), Q3 = *(const float4*)(qr + 12);
      float p[49];
      float mx = -1e30f;
#pragma unroll
      for (int mm = 0; mm < 49; mm++) {
        int m = mh * 49 + mm;
        const float* kr = &sK[m * 20];          // 2 addrs per wave -> broadcast
        float4 k0 = *(const float4*)kr, k1 = *(const float4*)(kr + 4);
        float4 k2 = *(const float4*)(kr + 8), k3 = *(const float4*)(kr + 12);
        float sv = Q0.x * k0.x + Q0.y * k0.y + Q0.z * k0.z + Q0.w * k0.w
                 + Q1.x * k1.x + Q1.y * k1.y + Q1.z * k1.z + Q1.w * k1.w
                 + Q2.x * k2.x + Q2.y * k2.y + Q2.z * k2.z + Q2.w * k2.w
                 + Q3.x * k3.x + Q3.y * k3.y + Q3.z * k3.z + Q3.w * k3.w;
        sv += rpb[(tn - sT[m]) * 4 + hd];
        p[mm] = sv;
        mx = fmaxf(mx, sv);
      }
      mx = fmaxf(mx, __shfl_xor(mx, 1));        // combine the two halves
      float sum = 0.f;
#pragma unroll
      for (int mm = 0; mm < 49; mm++) { float e = __expf(p[mm] - mx); p[mm] = e; sum += e; }
      sum += __shfl_xor(sum, 1);
      float inv = 1.f / sum;
      float4 o0 = make_float4(0, 0, 0, 0), o1 = o0, o2 = o0, o3 = o0;
#pragma unroll
      for (int mm = 0; mm < 49; mm++) {
        int m = mh * 49 + mm;
        float pv = p[mm];
        const float* vr = &sV[m * 20];          // broadcast
        float4 v0 = *(const float4*)vr, v1 = *(const float4*)(vr + 4);
        float4 v2 = *(const float4*)(vr + 8), v3 = *(const float4*)(vr + 12);
        o0.x += pv * v0.x; o0.y += pv * v0.y; o0.z += pv * v0.z; o0.w += pv * v0.w;
        o1.x += pv * v1.x; o1.y += pv * v1.y; o1.z += pv * v1.z; o1.w += pv * v1.w;
        o2.x += pv * v2.x; o2.y += pv * v2.y; o2.z += pv * v2.z; o2.w += pv * v2.w;
        o3.x += pv * v3.x; o3.y += pv * v3.y; o3.z += pv * v3.z; o3.w += pv * v3.w;
      }
      float* dp = &sPV[n * 40 + mh * 20];
      *(float4*)dp       = make_float4(o0.x * inv, o0.y * inv, o0.z * inv, o0.w * inv);
      *(float4*)(dp + 4) = make_float4(o1.x * inv, o1.y * inv, o1.z * inv, o1.w * inv);
      *(float4*)(dp + 8) = make_float4(o2.x * inv, o2.y * inv, o2.z * inv, o2.w * inv);
      *(float4*)(dp + 12)= make_float4(o3.x * inv, o3.y * inv, o3.z * inv, o3.w * inv);
    }
    __syncthreads();
    // fused projection over all 98 rows, no masking
#pragma unroll
    for (int k2 = 0; k2 < 4; k2++) {
      int u = k2 * 256 + tid;
      if (u < 784) {
        int nn = u >> 3, c8 = u & 7;
        const float* wrow = pw + hd * 16 * 64 + c8 * 8;
        const float* pv0 = &sPV[nn * 40];
#pragma unroll
        for (int j = 0; j < 16; j++) {
          float pv = pv0[j] + pv0[20 + j];
          float4 w0 = *(const float4*)(wrow + j * 64);
          float4 w1 = *(const float4*)(wrow + j * 64 + 4);
          pacc[k2][0] += pv * w0.x; pacc[k2][1] += pv * w0.y;
          pacc[k2][2] += pv * w0.z; pacc[k2][3] += pv * w0.w;
          pacc[k2][4] += pv * w1.x; pacc[k2][5] += pv * w1.y;
          pacc[k2][6] += pv * w1.z; pacc[k2][7] += pv * w1.w;
        }
      }
    }
    __syncthreads();
  }
  // write: acc[p*64 + c] += pacc + bias
  int b = wi >> 10, d0 = (wi >> 8) & 3, h0 = (wi >> 4) & 15, w0 = wi & 15;
#pragma unroll
  for (int k = 0; k < 4; k++) {
    int u = k * 256 + tid;
    if (u < 784) {
      int nn = u >> 3, c8 = u & 7;
      int dz = nn / 49, r = nn - dz * 49, oy = r / 7, ox = r - oy * 7;
      long p = ((long)(b * 8 + d0 * 2 + dz) * 112 + (h0 * 7 + oy)) * 112 + (w0 * 7 + ox);
      float* ap = accg + p * 64 + c8 * 8;
      float4 x0 = *(float4*)ap, x1 = *(float4*)(ap + 4);
      float4 pb0 = *(const float4*)(pb + c8 * 8), pb1 = *(const float4*)(pb + c8 * 8 + 4);
      x0.x += pacc[k][0] + pb0.x; x0.y += pacc[k][1] + pb0.y;
      x0.z += pacc[k][2] + pb0.z; x0.w += pacc[k][3] + pb0.w;
      x1.x += pacc[k][4] + pb1.x; x1.y += pacc[k][5] + pb1.y;
      x1.z += pacc[k][6] + pb1.z; x1.w += pacc[k][7] + pb1.w;
      *(float4*)ap = x0; *(float4*)(ap + 4) = x1;
    }
  }
}

// ---------------- Temporal attention: one wave per pixel sequence (D=8) ---------
__global__ __launch_bounds__(256) void k_tattn(const float* __restrict__ h, const float* __restrict__ qw,
    const float* __restrict__ qb, const float* __restrict__ rpbt, const float* __restrict__ pw,
    const float* __restrict__ pb, float* __restrict__ acc) {
  __shared__ float sm[4][1624];
  int wv = threadIdx.x >> 6, lane = threadIdx.x & 63;
  int s = blockIdx.x * 4 + wv;
  int b = s / 12544, rr = s - b * 12544, hy = rr / 112, wx = rr - hy * 112;
  float* xt = sm[wv];       // 8 x stride 65
  float* qkv = xt + 520;    // 8 x stride 97
  float* sp = qkv + 776;    // 64
  float* o = sp + 64;       // 8 x stride 33
  long pbase = ((long)b * 896 + hy) * 112 + wx;   // pos of token n = pbase + n*12544
  for (int i = lane; i < 512; i += 64) {
    int n = i >> 6, c = i & 63;
    xt[n * 65 + c] = h[(pbase + (long)n * 12544) * 64 + c];
  }
  __syncthreads();
  // qkv (8 x 96)
  for (int i = lane; i < 192; i += 64) {
    int n = i / 24, c4 = (i - n * 24) * 4;
    float4 a4 = *(const float4*)(qb + c4);
    float a0 = a4.x, a1 = a4.y, a2 = a4.z, a3 = a4.w;
    const float* xr = &xt[n * 65];
    const float* wp = qw + c4;
    for (int c = 0; c < 64; c++) {
      float xv = xr[c];
      float4 w4 = *(const float4*)(wp + c * 96);
      a0 += xv * w4.x; a1 += xv * w4.y;
      a2 += xv * w4.z; a3 += xv * w4.w;
    }
    float sc = (c4 < 32) ? 0.25f : 1.f;
    int ob = n * 97 + c4;
    qkv[ob] = a0 * sc; qkv[ob + 1] = a1 * sc; qkv[ob + 2] = a2 * sc; qkv[ob + 3] = a3 * sc;
  }
  __syncthreads();
  int n8 = lane >> 3, m8 = lane & 7;
  for (int hd = 0; hd < 4; hd++) {
    float sc = 0.f;
    const float* qr = &qkv[n8 * 97 + hd * 8];
    const float* kr = &qkv[m8 * 97 + 32 + hd * 8];
#pragma unroll
    for (int e = 0; e < 8; e++) sc += qr[e] * kr[e];
    sc += rpbt[(n8 - m8 + 7) * 4 + hd];
    sp[lane] = sc;
    __syncthreads();
    if (lane < 8) {
      float* row = &sp[lane * 8];
      float mx = -1e30f;
      for (int m = 0; m < 8; m++) mx = fmaxf(mx, row[m]);
      float sum = 0.f;
      for (int m = 0; m < 8; m++) { float e = __expf(row[m] - mx); row[m] = e; sum += e; }
      float inv = 1.f / sum;
      for (int m = 0; m < 8; m++) row[m] *= inv;
    }
    __syncthreads();
    float a = 0.f;
    const float* prow = &sp[n8 * 8];
#pragma unroll
    for (int m = 0; m < 8; m++) a += prow[m] * qkv[m * 97 + 64 + hd * 8 + m8];
    o[n8 * 33 + hd * 8 + m8] = a;
    __syncthreads();
  }
  // projection (32 -> 64), add into acc
  for (int i = lane; i < 128; i += 64) {
    int n = i >> 4, c4 = (i & 15) << 2;
    float4 a4 = *(const float4*)(pb + c4);
    float a0 = a4.x, a1 = a4.y, a2 = a4.z, a3 = a4.w;
    const float* orow = &o[n * 33];
    const float* wp = pw + c4;
    for (int k = 0; k < 32; k++) {
      float ov = orow[k];
      float4 w4 = *(const float4*)(wp + k * 64);
      a0 += ov * w4.x; a1 += ov * w4.y; a2 += ov * w4.z; a3 += ov * w4.w;
    }
    long ab = (pbase + (long)n * 12544) * 64 + c4;
    acc[ab] += a0; acc[ab + 1] += a1; acc[ab + 2] += a2; acc[ab + 3] += a3;
  }
}

// ---------------- Direct 3x3x3 conv, channels-last, 32ci -> 32co ----------------
// grid (2, 112, 16=b*8+d); block 256 = 8 w-groups x 32 co; each thread 8 outputs
__global__ __launch_bounds__(256) void k_conv(const float* __restrict__ in, int ics,
    const float* __restrict__ wgt, const float* __restrict__ bias,
    const float* __restrict__ addsrc, int acs, float* __restrict__ out, int lrelu) {
  __shared__ __align__(16) float s_in[32 * 68];
  __shared__ float s_w[32 * 97];
  int tid = threadIdx.x;
  int co = tid & 31, ws8 = tid >> 5;
  int wtile = blockIdx.x, hh = blockIdx.y, bz = blockIdx.z;
  int d = bz & 7, bb = bz >> 3;
  int wbase = wtile * 64;
  float acc[8];
#pragma unroll
  for (int q = 0; q < 8; q++) acc[q] = 0.f;
  for (int kd = 0; kd < 3; kd++) {
    int zd = d + kd - 1;
    if (zd < 0 || zd > 7) continue;
    for (int kh = 0; kh < 3; kh++) {
      int yy = hh + kh - 1;
      if (yy < 0 || yy > 111) continue;
      __syncthreads();
      int prow = ((bb * 8 + zd) * 112 + yy) * 112;
      for (int i = tid; i < 2112; i += 256) {
        int ci = i & 31, j = i >> 5;
        int w = wbase - 1 + j;
        float v = 0.f;
        if (w >= 0 && w < 112) v = in[(long)(prow + w) * ics + ci];
        s_in[ci * 68 + j] = v;
      }
      for (int i = tid; i < 3072; i += 256) {
        int c2 = i / 96, r = i - c2 * 96;
        int ci = r / 3, kw = r - ci * 3;
        s_w[c2 * 97 + r] = wgt[(c2 * 32 + ci) * 27 + kd * 9 + kh * 3 + kw];
      }
      __syncthreads();
      int jb = ws8 * 8;
      for (int ci = 0; ci < 32; ci++) {
        const float* ip = &s_in[ci * 68 + jb];
        float4 A = *(const float4*)ip;
        float4 Bv = *(const float4*)(ip + 4);
        float2 Cv = *(const float2*)(ip + 8);
        float v[10] = {A.x, A.y, A.z, A.w, Bv.x, Bv.y, Bv.z, Bv.w, Cv.x, Cv.y};
        const float* wr = &s_w[co * 97 + ci * 3];
        float w0 = wr[0], w1 = wr[1], w2 = wr[2];
#pragma unroll
        for (int q = 0; q < 8; q++)
          acc[q] += v[q] * w0 + v[q + 1] * w1 + v[q + 2] * w2;
      }
    }
  }
  float bv = bias[co];
  int w00 = wbase + ws8 * 8;
  int pcol = (bz * 112 + hh) * 112;
#pragma unroll
  for (int q = 0; q < 8; q++) {
    int w = w00 + q;
    if (w < 112) {
      float vv = acc[q] + bv;
      if (lrelu) vv = vv > 0.f ? vv : 0.01f * vv;
      long pos = pcol + w;
      if (addsrc) vv += addsrc[pos * acs + co];
      out[pos * 32 + co] = vv;
    }
  }
}

// ---------------- x2 += y1 (in place in h2's channel 32..63) --------------------
__global__ __launch_bounds__(256) void k_addx2(float* __restrict__ h2, const float* __restrict__ y1) {
  long i = (long)blockIdx.x * 256 + threadIdx.x;
  long pos = i >> 5;
  int c = (int)(i & 31);
  h2[pos * 64 + 32 + c] += y1[i];
}

// ---------------- out = acc + concat(y1,y2) -------------------------------------
__global__ __launch_bounds__(256) void k_final(const float* __restrict__ acc, const float* __restrict__ y1,
    const float* __restrict__ y2, float* __restrict__ out) {
  long i = (long)blockIdx.x * 256 + threadIdx.x;
  long pos = i >> 6;
  int c = (int)(i & 63);
  float v = acc[i] + (c < 32 ? y1[pos * 32 + c] : y2[pos * 32 + c - 32]);
  out[i] = v;
}

extern "C" void kernel_launch(void* const* d_in, const int* in_sizes, int n_in,
                              void* d_out, int out_size, void* d_ws, size_t ws_size,
                              hipStream_t stream) {
  const float* x        = (const float*)d_in[0];
  // d_in[1] mask_matrix: unused (all zeros in reference path)
  const float* g1       = (const float*)d_in[2];
  const float* b1       = (const float*)d_in[3];
  const float* rpb_s    = (const float*)d_in[4];
  const float* qkv_w_s  = (const float*)d_in[5];
  const float* qkv_b_s  = (const float*)d_in[6];
  const float* proj_w_s = (const float*)d_in[7];
  const float* proj_b_s = (const float*)d_in[8];
  const float* rpb_t    = (const float*)d_in[9];
  const float* qkv_w_t  = (const float*)d_in[10];
  const float* qkv_b_t  = (const float*)d_in[11];
  const float* proj_w_t = (const float*)d_in[12];
  const float* proj_b_t = (const float*)d_in[13];
  const float* g2       = (const float*)d_in[14];
  const float* b2       = (const float*)d_in[15];
  const float* c1w = (const float*)d_in[16];
  const float* c1b = (const float*)d_in[17];
  const float* c2w = (const float*)d_in[18];
  const float* c2b = (const float*)d_in[19];
  const float* c3w = (const float*)d_in[20];
  const float* c3b = (const float*)d_in[21];
  const float* c4w = (const float*)d_in[22];
  const float* c4b = (const float*)d_in[23];

  // workspace (fp32 elems): acc(12.8M) | hbuf(12.8M) | C region (19.3M floats)
  // C region: first QKV bf16 (3 x 12.8M u16 = exact fit), later tbuf/y1/y2 for convs
  float* acc  = (float*)d_ws;
  float* hbuf = acc + 12845056;
  float* creg = hbuf + 12845056;
  u16* Qg = (u16*)creg;
  u16* Kg = Qg + 12845056;
  u16* Vg = Kg + 12845056;
  float* tbuf = creg;
  float* y1   = creg + 6422528;
  float* y2   = y1 + 6422528;

  // 1. LN1: h = LN(x); acc = x
  k_ln<<<50176, 256, 0, stream>>>(x, g1, b1, hbuf, acc);
  // 2. spatial qkv (dense GEMM) -> bf16 windowed Q/K/V
  k_qkvs<<<6272, 256, 0, stream>>>(hbuf, qkv_w_s, qkv_b_s, Qg, Kg, Vg);
  // 3. spatial attention + fused projection, acc += (one block per window)
  k_sattn2<<<2048, 256, 0, stream>>>(Qg, Kg, Vg, rpb_s, proj_w_s, proj_b_s, acc);
  // 4. temporal attention, add into acc
  k_tattn<<<6272, 256, 0, stream>>>(hbuf, qkv_w_t, qkv_b_t, rpb_t, proj_w_t, proj_b_t, acc);
  // 5. LN2: h2 = LN(acc)
  k_ln<<<50176, 256, 0, stream>>>(acc, g2, b2, hbuf, nullptr);
  // 6. conv path 1: t = lrelu(conv(x1)); y1 = x1 + conv(t)
  k_conv<<<dim3(2, 112, 16), 256, 0, stream>>>(hbuf, 64, c1w, c1b, nullptr, 0, tbuf, 1);
  k_conv<<<dim3(2, 112, 16), 256, 0, stream>>>(tbuf, 32, c2w, c2b, hbuf, 64, y1, 0);
  // 7. x2 += y1 (in place)
  k_addx2<<<25088, 256, 0, stream>>>(hbuf, y1);
  // 8. conv path 2: t = lrelu(conv(x2b)); y2 = x2b + conv(t)
  k_conv<<<dim3(2, 112, 16), 256, 0, stream>>>(hbuf + 32, 64, c3w, c3b, nullptr, 0, tbuf, 1);
  k_conv<<<dim3(2, 112, 16), 256, 0, stream>>>(tbuf, 32, c4w, c4b, hbuf + 32, 64, y2, 0);
  // 9. out = acc + concat(y1, y2)
  k_final<<<50176, 256, 0, stream>>>(acc, y1, y2, (float*)d_out);
}

// Round 7
// 798.853 us; speedup vs baseline: 5.7483x; 3.1527x over previous
//
#include <hip/hip_runtime.h>
#include <hip/hip_bf16.h>

typedef unsigned short u16;
typedef unsigned int u32;
typedef __attribute__((ext_vector_type(8))) short s16x8;
typedef __attribute__((ext_vector_type(4))) float f32x4;

__device__ __forceinline__ u16 f2b(float v) {
  u32 bits = __float_as_uint(v);
  bits += 0x7fffu + ((bits >> 16) & 1u);
  return (u16)(bits >> 16);
}
__device__ __forceinline__ float b2f(u16 u) { return __uint_as_float(((u32)u) << 16); }

// ---------------- LayerNorm: writes h (f32), optionally acc=x, optionally bf16 ch0..31
__global__ __launch_bounds__(256) void k_ln(const float* __restrict__ x, const float* __restrict__ g,
    const float* __restrict__ b, float* __restrict__ hout, float* __restrict__ acc, u16* __restrict__ xb) {
  int token = blockIdx.x * 4 + (threadIdx.x >> 6);
  int lane = threadIdx.x & 63;
  long base = (long)token * 64 + lane;
  float v = x[base];
  float s = v;
#pragma unroll
  for (int o = 32; o; o >>= 1) s += __shfl_xor(s, o);
  float m = s * 0.015625f;
  float d = v - m;
  float q = d * d;
#pragma unroll
  for (int o = 32; o; o >>= 1) q += __shfl_xor(q, o);
  float r = rsqrtf(q * 0.015625f + 1e-5f);
  float hv = d * r * g[lane] + b[lane];
  hout[base] = hv;
  if (acc) acc[base] = v;
  if (xb && lane < 32) xb[(long)token * 32 + lane] = f2b(hv);
}

// ---------------- Spatial qkv: dense GEMM, h read once, bf16 windowed output ----
__global__ __launch_bounds__(256) void k_qkvs(const float* __restrict__ h, const float* __restrict__ qw,
    const float* __restrict__ qb, u16* __restrict__ Qg, u16* __restrict__ Kg, u16* __restrict__ Vg) {
  __shared__ float sx[4][512];
  int wv = threadIdx.x >> 6, lane = threadIdx.x & 63;
  long t0 = (long)blockIdx.x * 32 + wv * 8;
  for (int i = lane; i < 512; i += 64) sx[wv][i] = h[t0 * 64 + i];
  __syncthreads();
  float aq[8], ak[8], av[8];
  float bq = qb[lane], bk = qb[64 + lane], bv = qb[128 + lane];
#pragma unroll
  for (int i = 0; i < 8; i++) { aq[i] = bq; ak[i] = bk; av[i] = bv; }
  for (int k = 0; k < 64; k++) {
    float wq = qw[k * 192 + lane];
    float wk = qw[k * 192 + 64 + lane];
    float wvv = qw[k * 192 + 128 + lane];
#pragma unroll
    for (int i = 0; i < 8; i++) {
      float xv = sx[wv][i * 64 + k];
      aq[i] += xv * wq; ak[i] += xv * wk; av[i] += xv * wvv;
    }
  }
  int hd = lane >> 4, j = lane & 15;
#pragma unroll
  for (int i = 0; i < 8; i++) {
    long p = t0 + i;
    int b = (int)(p / 100352); int r = (int)(p - (long)b * 100352);
    int d = r / 12544; int r2 = r - d * 12544;
    int hy = r2 / 112, wx = r2 - hy * 112;
    int d0 = d >> 1, dz = d & 1, h0 = hy / 7, oy = hy - h0 * 7, w0 = wx / 7, ox = wx - w0 * 7;
    int wi = ((b * 4 + d0) * 16 + h0) * 16 + w0;
    int n = dz * 49 + oy * 7 + ox;
    long o = (long)(wi * 4 + hd) * 1568 + n * 16 + j;
    Qg[o] = f2b(aq[i] * 0.25f);
    Kg[o] = f2b(ak[i]);
    Vg[o] = f2b(av[i]);
  }
}

// ---------------- Spatial attention + fused projection: one block per window ----
__global__ __launch_bounds__(256) void k_sattn2(const u16* __restrict__ Qg, const u16* __restrict__ Kg,
    const u16* __restrict__ Vg, const float* __restrict__ rpb, const float* __restrict__ pw,
    const float* __restrict__ pb, float* __restrict__ accg) {
  __shared__ __align__(16) float sQ[98 * 20];
  __shared__ __align__(16) float sK[98 * 20];
  __shared__ __align__(16) float sV[98 * 20];
  __shared__ __align__(16) float sPV[98 * 40];   // [n][mh*20 + e]
  __shared__ int sT[128];
  int tid = threadIdx.x;
  int wi = blockIdx.x;
  if (tid < 98) {
    int dz = tid / 49, r = tid - dz * 49, hy = r / 7, wx = r - hy * 7;
    sT[tid] = dz * 169 + hy * 13 + wx;
  } else if (tid < 128) sT[tid] = 0;
  int n = tid >> 1;
  int mh = tid & 1;
  bool act = tid < 196;
  float pacc[4][8];
#pragma unroll
  for (int k = 0; k < 4; k++)
#pragma unroll
    for (int e = 0; e < 8; e++) pacc[k][e] = 0.f;
  __syncthreads();
  int tn = sT[n] + 253;

  for (int hd = 0; hd < 4; hd++) {
    long base = (long)(wi * 4 + hd) * 1568;
    for (int i = tid; i < 1568; i += 256) { int r = i >> 4, j = i & 15; sQ[r * 20 + j] = b2f(Qg[base + i]); }
    for (int i = tid; i < 1568; i += 256) { int r = i >> 4, j = i & 15; sK[r * 20 + j] = b2f(Kg[base + i]); }
    for (int i = tid; i < 1568; i += 256) { int r = i >> 4, j = i & 15; sV[r * 20 + j] = b2f(Vg[base + i]); }
    __syncthreads();
    if (act) {
      const float* qr = &sQ[n * 20];
      float4 Q0 = *(const float4*)qr, Q1 = *(const float4*)(qr + 4);
      float4 Q2 = *(const float4*)(qr + 8), Q3 = *(const float4*)(qr + 12);
      float p[49];
      float mx = -1e30f;
#pragma unroll
      for (int mm = 0; mm < 49; mm++) {
        int m = mh * 49 + mm;
        const float* kr = &sK[m * 20];
        float4 k0 = *(const float4*)kr, k1 = *(const float4*)(kr + 4);
        float4 k2 = *(const float4*)(kr + 8), k3 = *(const float4*)(kr + 12);
        float sv = Q0.x * k0.x + Q0.y * k0.y + Q0.z * k0.z + Q0.w * k0.w
                 + Q1.x * k1.x + Q1.y * k1.y + Q1.z * k1.z + Q1.w * k1.w
                 + Q2.x * k2.x + Q2.y * k2.y + Q2.z * k2.z + Q2.w * k2.w
                 + Q3.x * k3.x + Q3.y * k3.y + Q3.z * k3.z + Q3.w * k3.w;
        sv += rpb[(tn - sT[m]) * 4 + hd];
        p[mm] = sv;
        mx = fmaxf(mx, sv);
      }
      mx = fmaxf(mx, __shfl_xor(mx, 1));
      float sum = 0.f;
#pragma unroll
      for (int mm = 0; mm < 49; mm++) { float e = __expf(p[mm] - mx); p[mm] = e; sum += e; }
      sum += __shfl_xor(sum, 1);
      float inv = 1.f / sum;
      float4 o0 = make_float4(0, 0, 0, 0), o1 = o0, o2 = o0, o3 = o0;
#pragma unroll
      for (int mm = 0; mm < 49; mm++) {
        int m = mh * 49 + mm;
        float pv = p[mm];
        const float* vr = &sV[m * 20];
        float4 v0 = *(const float4*)vr, v1 = *(const float4*)(vr + 4);
        float4 v2 = *(const float4*)(vr + 8), v3 = *(const float4*)(vr + 12);
        o0.x += pv * v0.x; o0.y += pv * v0.y; o0.z += pv * v0.z; o0.w += pv * v0.w;
        o1.x += pv * v1.x; o1.y += pv * v1.y; o1.z += pv * v1.z; o1.w += pv * v1.w;
        o2.x += pv * v2.x; o2.y += pv * v2.y; o2.z += pv * v2.z; o2.w += pv * v2.w;
        o3.x += pv * v3.x; o3.y += pv * v3.y; o3.z += pv * v3.z; o3.w += pv * v3.w;
      }
      float* dp = &sPV[n * 40 + mh * 20];
      *(float4*)dp       = make_float4(o0.x * inv, o0.y * inv, o0.z * inv, o0.w * inv);
      *(float4*)(dp + 4) = make_float4(o1.x * inv, o1.y * inv, o1.z * inv, o1.w * inv);
      *(float4*)(dp + 8) = make_float4(o2.x * inv, o2.y * inv, o2.z * inv, o2.w * inv);
      *(float4*)(dp + 12)= make_float4(o3.x * inv, o3.y * inv, o3.z * inv, o3.w * inv);
    }
    __syncthreads();
#pragma unroll
    for (int k2 = 0; k2 < 4; k2++) {
      int u = k2 * 256 + tid;
      if (u < 784) {
        int nn = u >> 3, c8 = u & 7;
        const float* wrow = pw + hd * 16 * 64 + c8 * 8;
        const float* pv0 = &sPV[nn * 40];
#pragma unroll
        for (int j = 0; j < 16; j++) {
          float pv = pv0[j] + pv0[20 + j];
          float4 w0 = *(const float4*)(wrow + j * 64);
          float4 w1 = *(const float4*)(wrow + j * 64 + 4);
          pacc[k2][0] += pv * w0.x; pacc[k2][1] += pv * w0.y;
          pacc[k2][2] += pv * w0.z; pacc[k2][3] += pv * w0.w;
          pacc[k2][4] += pv * w1.x; pacc[k2][5] += pv * w1.y;
          pacc[k2][6] += pv * w1.z; pacc[k2][7] += pv * w1.w;
        }
      }
    }
    __syncthreads();
  }
  int b = wi >> 10, d0 = (wi >> 8) & 3, h0 = (wi >> 4) & 15, w0 = wi & 15;
#pragma unroll
  for (int k = 0; k < 4; k++) {
    int u = k * 256 + tid;
    if (u < 784) {
      int nn = u >> 3, c8 = u & 7;
      int dz = nn / 49, r = nn - dz * 49, oy = r / 7, ox = r - oy * 7;
      long p = ((long)(b * 8 + d0 * 2 + dz) * 112 + (h0 * 7 + oy)) * 112 + (w0 * 7 + ox);
      float* ap = accg + p * 64 + c8 * 8;
      float4 x0 = *(float4*)ap, x1 = *(float4*)(ap + 4);
      float4 pb0 = *(const float4*)(pb + c8 * 8), pb1 = *(const float4*)(pb + c8 * 8 + 4);
      x0.x += pacc[k][0] + pb0.x; x0.y += pacc[k][1] + pb0.y;
      x0.z += pacc[k][2] + pb0.z; x0.w += pacc[k][3] + pb0.w;
      x1.x += pacc[k][4] + pb1.x; x1.y += pacc[k][5] + pb1.y;
      x1.z += pacc[k][6] + pb1.z; x1.w += pacc[k][7] + pb1.w;
      *(float4*)ap = x0; *(float4*)(ap + 4) = x1;
    }
  }
}

// ---------------- Temporal attention: one wave per pixel sequence (D=8) ---------
__global__ __launch_bounds__(256) void k_tattn(const float* __restrict__ h, const float* __restrict__ qw,
    const float* __restrict__ qb, const float* __restrict__ rpbt, const float* __restrict__ pw,
    const float* __restrict__ pb, float* __restrict__ acc) {
  __shared__ float sm[4][1624];
  int wv = threadIdx.x >> 6, lane = threadIdx.x & 63;
  int s = blockIdx.x * 4 + wv;
  int b = s / 12544, rr = s - b * 12544, hy = rr / 112, wx = rr - hy * 112;
  float* xt = sm[wv];
  float* qkv = xt + 520;
  float* sp = qkv + 776;
  float* o = sp + 64;
  long pbase = ((long)b * 896 + hy) * 112 + wx;
  for (int i = lane; i < 512; i += 64) {
    int n = i >> 6, c = i & 63;
    xt[n * 65 + c] = h[(pbase + (long)n * 12544) * 64 + c];
  }
  __syncthreads();
  for (int i = lane; i < 192; i += 64) {
    int n = i / 24, c4 = (i - n * 24) * 4;
    float4 a4 = *(const float4*)(qb + c4);
    float a0 = a4.x, a1 = a4.y, a2 = a4.z, a3 = a4.w;
    const float* xr = &xt[n * 65];
    const float* wp = qw + c4;
    for (int c = 0; c < 64; c++) {
      float xv = xr[c];
      float4 w4 = *(const float4*)(wp + c * 96);
      a0 += xv * w4.x; a1 += xv * w4.y;
      a2 += xv * w4.z; a3 += xv * w4.w;
    }
    float sc = (c4 < 32) ? 0.25f : 1.f;
    int ob = n * 97 + c4;
    qkv[ob] = a0 * sc; qkv[ob + 1] = a1 * sc; qkv[ob + 2] = a2 * sc; qkv[ob + 3] = a3 * sc;
  }
  __syncthreads();
  int n8 = lane >> 3, m8 = lane & 7;
  for (int hd = 0; hd < 4; hd++) {
    float sc = 0.f;
    const float* qr = &qkv[n8 * 97 + hd * 8];
    const float* kr = &qkv[m8 * 97 + 32 + hd * 8];
#pragma unroll
    for (int e = 0; e < 8; e++) sc += qr[e] * kr[e];
    sc += rpbt[(n8 - m8 + 7) * 4 + hd];
    sp[lane] = sc;
    __syncthreads();
    if (lane < 8) {
      float* row = &sp[lane * 8];
      float mx = -1e30f;
      for (int m = 0; m < 8; m++) mx = fmaxf(mx, row[m]);
      float sum = 0.f;
      for (int m = 0; m < 8; m++) { float e = __expf(row[m] - mx); row[m] = e; sum += e; }
      float inv = 1.f / sum;
      for (int m = 0; m < 8; m++) row[m] *= inv;
    }
    __syncthreads();
    float a = 0.f;
    const float* prow = &sp[n8 * 8];
#pragma unroll
    for (int m = 0; m < 8; m++) a += prow[m] * qkv[m * 97 + 64 + hd * 8 + m8];
    o[n8 * 33 + hd * 8 + m8] = a;
    __syncthreads();
  }
  for (int i = lane; i < 128; i += 64) {
    int n = i >> 4, c4 = (i & 15) << 2;
    float4 a4 = *(const float4*)(pb + c4);
    float a0 = a4.x, a1 = a4.y, a2 = a4.z, a3 = a4.w;
    const float* orow = &o[n * 33];
    const float* wp = pw + c4;
    for (int k = 0; k < 32; k++) {
      float ov = orow[k];
      float4 w4 = *(const float4*)(wp + k * 64);
      a0 += ov * w4.x; a1 += ov * w4.y; a2 += ov * w4.z; a3 += ov * w4.w;
    }
    long ab = (pbase + (long)n * 12544) * 64 + c4;
    acc[ab] += a0; acc[ab + 1] += a1; acc[ab + 2] += a2; acc[ab + 3] += a3;
  }
}

// ---------------- Weight prepack: OIDHW f32 -> WB[kk][co][ci] bf16 --------------
__global__ __launch_bounds__(256) void k_wprep(const float* __restrict__ w0, const float* __restrict__ w1,
    const float* __restrict__ w2, const float* __restrict__ w3, u16* __restrict__ WB) {
  int c = blockIdx.y;
  int i = blockIdx.x * 256 + threadIdx.x;   // < 27648
  const float* src = c == 0 ? w0 : c == 1 ? w1 : c == 2 ? w2 : w3;
  int co = i / 864, rem = i - co * 864, ci = rem / 27, kk = rem - ci * 27;
  WB[c * 27648 + kk * 1024 + co * 32 + ci] = f2b(src[i]);
}

// ---------------- MFMA implicit-GEMM 3x3x3 conv, 32ci->32co, bf16 in, fp32 acc --
// 1 wave per output row (bz,hh); 7 M-tiles of 16 w; A from global (masked),
// B from prepacked WB; epilogue by mode: 1 = lrelu->bf16(outb),
// 2 = conv2 fused residuals, 4 = conv4 fused final store.
__global__ __launch_bounds__(64) void k_convm(const u16* __restrict__ in, const u16* __restrict__ wb,
    const float* __restrict__ bias, int mode,
    const float* __restrict__ hbuf, const float* __restrict__ accb,
    float* __restrict__ dout, float* __restrict__ x2f, u16* __restrict__ outb) {
  int row = blockIdx.x;
  int hh = row % 112, bz = row / 112;
  int d = bz & 7, bb = bz >> 3;
  long prow = (long)row * 112;
  int l = threadIdx.x, lm = l & 15, lk = l >> 4;
  f32x4 acc[7][2];
#pragma unroll
  for (int t = 0; t < 7; t++) { acc[t][0] = (f32x4){0.f,0.f,0.f,0.f}; acc[t][1] = (f32x4){0.f,0.f,0.f,0.f}; }
  for (int kd = 0; kd < 3; kd++) {
    int zd = d + kd - 1;
    if (zd < 0 || zd > 7) continue;
    for (int kh = 0; kh < 3; kh++) {
      int yy = hh + kh - 1;
      if (yy < 0 || yy > 111) continue;
      const u16* ip = in + ((long)((bb * 8 + zd) * 112 + yy)) * 112 * 32;
      int kkb = kd * 9 + kh * 3;
      s16x8 B0[3], B1[3];
#pragma unroll
      for (int kw = 0; kw < 3; kw++) {
        const u16* wp = wb + (kkb + kw) * 1024 + lk * 8;
        B0[kw] = *(const s16x8*)(wp + lm * 32);
        B1[kw] = *(const s16x8*)(wp + (16 + lm) * 32);
      }
#pragma unroll
      for (int t = 0; t < 7; t++) {
#pragma unroll
        for (int kw = 0; kw < 3; kw++) {
          int w = t * 16 + lm + kw - 1;
          s16x8 A = {};
          if ((unsigned)w < 112u) A = *(const s16x8*)(ip + (long)w * 32 + lk * 8);
          acc[t][0] = __builtin_amdgcn_mfma_f32_16x16x32_bf16(A, B0[kw], acc[t][0], 0, 0, 0);
          acc[t][1] = __builtin_amdgcn_mfma_f32_16x16x32_bf16(A, B1[kw], acc[t][1], 0, 0, 0);
        }
      }
    }
  }
  float b0 = bias[lm], b1 = bias[16 + lm];
#pragma unroll
  for (int t = 0; t < 7; t++) {
#pragma unroll
    for (int r = 0; r < 4; r++) {
      long pos = prow + t * 16 + lk * 4 + r;
      float v0 = acc[t][0][r] + b0;
      float v1 = acc[t][1][r] + b1;
      if (mode == 1) {
        v0 = v0 > 0.f ? v0 : 0.01f * v0;
        v1 = v1 > 0.f ? v1 : 0.01f * v1;
        outb[pos * 32 + lm] = f2b(v0);
        outb[pos * 32 + 16 + lm] = f2b(v1);
      } else if (mode == 2) {
        float y0 = v0 + hbuf[pos * 64 + lm];
        float y1v = v1 + hbuf[pos * 64 + 16 + lm];
        dout[pos * 64 + lm] = accb[pos * 64 + lm] + y0;
        dout[pos * 64 + 16 + lm] = accb[pos * 64 + 16 + lm] + y1v;
        float t0 = hbuf[pos * 64 + 32 + lm] + y0;
        float t1 = hbuf[pos * 64 + 48 + lm] + y1v;
        x2f[pos * 32 + lm] = t0;
        x2f[pos * 32 + 16 + lm] = t1;
        outb[pos * 32 + lm] = f2b(t0);
        outb[pos * 32 + 16 + lm] = f2b(t1);
      } else {
        float y0 = v0 + x2f[pos * 32 + lm];
        float y1v = v1 + x2f[pos * 32 + 16 + lm];
        dout[pos * 64 + 32 + lm] = accb[pos * 64 + 32 + lm] + y0;
        dout[pos * 64 + 48 + lm] = accb[pos * 64 + 48 + lm] + y1v;
      }
    }
  }
}

extern "C" void kernel_launch(void* const* d_in, const int* in_sizes, int n_in,
                              void* d_out, int out_size, void* d_ws, size_t ws_size,
                              hipStream_t stream) {
  const float* x        = (const float*)d_in[0];
  // d_in[1] mask_matrix: unused (all zeros in reference path)
  const float* g1       = (const float*)d_in[2];
  const float* b1       = (const float*)d_in[3];
  const float* rpb_s    = (const float*)d_in[4];
  const float* qkv_w_s  = (const float*)d_in[5];
  const float* qkv_b_s  = (const float*)d_in[6];
  const float* proj_w_s = (const float*)d_in[7];
  const float* proj_b_s = (const float*)d_in[8];
  const float* rpb_t    = (const float*)d_in[9];
  const float* qkv_w_t  = (const float*)d_in[10];
  const float* qkv_b_t  = (const float*)d_in[11];
  const float* proj_w_t = (const float*)d_in[12];
  const float* proj_b_t = (const float*)d_in[13];
  const float* g2       = (const float*)d_in[14];
  const float* b2       = (const float*)d_in[15];
  const float* c1w = (const float*)d_in[16];
  const float* c1b = (const float*)d_in[17];
  const float* c2w = (const float*)d_in[18];
  const float* c2b = (const float*)d_in[19];
  const float* c3w = (const float*)d_in[20];
  const float* c3b = (const float*)d_in[21];
  const float* c4w = (const float*)d_in[22];
  const float* c4b = (const float*)d_in[23];

  // workspace (fp32 elems): acc(12.8M) | hbuf(12.8M) | creg(19.27M)
  // creg during attention: Qg|Kg|Vg bf16 (3 x 12.8M u16)
  // creg during convs:     x1b|t_b|x2b bf16 + x2f f32 + WB bf16
  float* acc  = (float*)d_ws;
  float* hbuf = acc + 12845056;
  float* creg = hbuf + 12845056;
  u16* Qg = (u16*)creg;
  u16* Kg = Qg + 12845056;
  u16* Vg = Kg + 12845056;
  u16* x1b = (u16*)creg;               // 6422528 u16
  u16* t_b = x1b + 6422528;            // 6422528 u16
  u16* x2b = t_b + 6422528;            // 6422528 u16
  float* x2f = (float*)(x2b + 6422528);// 6422528 f32
  u16* WB = (u16*)(x2f + 6422528);     // 4 x 27648 u16
  float* dout = (float*)d_out;

  // 1. LN1: h = LN(x); acc = x
  k_ln<<<50176, 256, 0, stream>>>(x, g1, b1, hbuf, acc, nullptr);
  // 2. spatial qkv (dense GEMM) -> bf16 windowed Q/K/V
  k_qkvs<<<6272, 256, 0, stream>>>(hbuf, qkv_w_s, qkv_b_s, Qg, Kg, Vg);
  // 3. spatial attention + fused projection, acc += (one block per window)
  k_sattn2<<<2048, 256, 0, stream>>>(Qg, Kg, Vg, rpb_s, proj_w_s, proj_b_s, acc);
  // 4. temporal attention, add into acc
  k_tattn<<<6272, 256, 0, stream>>>(hbuf, qkv_w_t, qkv_b_t, rpb_t, proj_w_t, proj_b_t, acc);
  // 5. weight prepack (after attention: WB region overlapped Vg)
  k_wprep<<<dim3(108, 4), 256, 0, stream>>>(c1w, c2w, c3w, c4w, WB);
  // 6. LN2: h2 = LN(acc) -> hbuf f32 + x1b bf16 (ch 0..31)
  k_ln<<<50176, 256, 0, stream>>>(acc, g2, b2, hbuf, nullptr, x1b);
  // 7. conv path 1: t = lrelu(conv(x1)) -> t_b bf16
  k_convm<<<1792, 64, 0, stream>>>(x1b, WB, c1b, 1, nullptr, nullptr, nullptr, nullptr, t_b);
  // 8. conv2 + fused: y1 = x1 + conv(t); dout(ch0..31)=acc+y1; x2f/x2b = h2[32:]+y1
  k_convm<<<1792, 64, 0, stream>>>(t_b, WB + 27648, c2b, 2, hbuf, acc, dout, x2f, x2b);
  // 9. conv path 2: t = lrelu(conv(x2b)) -> t_b bf16
  k_convm<<<1792, 64, 0, stream>>>(x2b, WB + 2 * 27648, c3b, 1, nullptr, nullptr, nullptr, nullptr, t_b);
  // 10. conv4 + fused: y2 = x2 + conv(t); dout(ch32..63) = acc + y2
  k_convm<<<1792, 64, 0, stream>>>(t_b, WB + 3 * 27648, c4b, 4, nullptr, acc, dout, x2f, nullptr);
}

// Round 9
// 706.343 us; speedup vs baseline: 6.5011x; 1.1310x over previous
//
#include <hip/hip_runtime.h>
#include <hip/hip_bf16.h>

typedef unsigned short u16;
typedef unsigned int u32;
typedef __attribute__((ext_vector_type(8))) short s16x8;
typedef __attribute__((ext_vector_type(4))) float f32x4;

__device__ __forceinline__ u16 f2b(float v) {
  u32 bits = __float_as_uint(v);
  bits += 0x7fffu + ((bits >> 16) & 1u);
  return (u16)(bits >> 16);
}
__device__ __forceinline__ float b2f(u16 u) { return __uint_as_float(((u32)u) << 16); }

// ---------------- LayerNorm: writes h (f32), optionally acc=x, optionally bf16 ch0..31
__global__ __launch_bounds__(256) void k_ln(const float* __restrict__ x, const float* __restrict__ g,
    const float* __restrict__ b, float* __restrict__ hout, float* __restrict__ acc, u16* __restrict__ xb) {
  int token = blockIdx.x * 4 + (threadIdx.x >> 6);
  int lane = threadIdx.x & 63;
  long base = (long)token * 64 + lane;
  float v = x[base];
  float s = v;
#pragma unroll
  for (int o = 32; o; o >>= 1) s += __shfl_xor(s, o);
  float m = s * 0.015625f;
  float d = v - m;
  float q = d * d;
#pragma unroll
  for (int o = 32; o; o >>= 1) q += __shfl_xor(q, o);
  float r = rsqrtf(q * 0.015625f + 1e-5f);
  float hv = d * r * g[lane] + b[lane];
  hout[base] = hv;
  if (acc) acc[base] = v;
  if (xb && lane < 32) xb[(long)token * 32 + lane] = f2b(hv);
}

// ---------------- Spatial qkv: dense GEMM, h read once, bf16 windowed output ----
__global__ __launch_bounds__(256) void k_qkvs(const float* __restrict__ h, const float* __restrict__ qw,
    const float* __restrict__ qb, u16* __restrict__ Qg, u16* __restrict__ Kg, u16* __restrict__ Vg) {
  __shared__ float sx[4][512];
  int wv = threadIdx.x >> 6, lane = threadIdx.x & 63;
  long t0 = (long)blockIdx.x * 32 + wv * 8;
  for (int i = lane; i < 512; i += 64) sx[wv][i] = h[t0 * 64 + i];
  __syncthreads();
  float aq[8], ak[8], av[8];
  float bq = qb[lane], bk = qb[64 + lane], bv = qb[128 + lane];
#pragma unroll
  for (int i = 0; i < 8; i++) { aq[i] = bq; ak[i] = bk; av[i] = bv; }
  for (int k = 0; k < 64; k++) {
    float wq = qw[k * 192 + lane];
    float wk = qw[k * 192 + 64 + lane];
    float wvv = qw[k * 192 + 128 + lane];
#pragma unroll
    for (int i = 0; i < 8; i++) {
      float xv = sx[wv][i * 64 + k];
      aq[i] += xv * wq; ak[i] += xv * wk; av[i] += xv * wvv;
    }
  }
  int hd = lane >> 4, j = lane & 15;
#pragma unroll
  for (int i = 0; i < 8; i++) {
    long p = t0 + i;
    int b = (int)(p / 100352); int r = (int)(p - (long)b * 100352);
    int d = r / 12544; int r2 = r - d * 12544;
    int hy = r2 / 112, wx = r2 - hy * 112;
    int d0 = d >> 1, dz = d & 1, h0 = hy / 7, oy = hy - h0 * 7, w0 = wx / 7, ox = wx - w0 * 7;
    int wi = ((b * 4 + d0) * 16 + h0) * 16 + w0;
    int n = dz * 49 + oy * 7 + ox;
    long o = (long)(wi * 4 + hd) * 1568 + n * 16 + j;
    Qg[o] = f2b(aq[i] * 0.25f);
    Kg[o] = f2b(ak[i]);
    Vg[o] = f2b(av[i]);
  }
}

// ---------------- proj weight prepack to B-frag layout (global scratch) ---------
__global__ __launch_bounds__(256) void k_pwprep(const float* __restrict__ pw, u16* __restrict__ pwb) {
  int i = blockIdx.x * 256 + threadIdx.x;   // < 4096
  int r = i & 7, q = i >> 3;
  int col = q & 15; q >>= 4;
  int lk = q & 1; q >>= 1;
  int nt = q & 3, hd = q >> 2;
  pwb[i] = f2b(pw[(hd * 16 + lk * 8 + r) * 64 + nt * 16 + col]);
}

// ---------------- MFMA spatial attention + fused projection: 1 block per window -
// 4 waves; M padded 98->112 (7 tiles), wave w owns tiles {w, w+4}.
// All LDS vector reads are within-row and within-own-tile (round-8 NaN was an
// out-of-row PV overread into another wave's tile: stale bf16 NaN * 0 = NaN).
__global__ __launch_bounds__(256) void k_sattn3(const u16* __restrict__ Qg, const u16* __restrict__ Kg,
    const u16* __restrict__ Vg, const float* __restrict__ rpb, const u16* __restrict__ pwb,
    const float* __restrict__ pb, float* __restrict__ accg) {
  __shared__ __align__(16) u16 sQ[112 * 24];
  __shared__ __align__(16) u16 sK[112 * 24];
  __shared__ __align__(16) u16 sVt[16 * 136];
  __shared__ __align__(16) u16 sP[112 * 120 + 32];
  __shared__ __align__(16) u16 sO[112 * 24];
  __shared__ int sT[112];
  int tid = threadIdx.x;
  int wi = blockIdx.x;
  int l = tid & 63, wv = tid >> 6;
  int lm = l & 15, lk = l >> 4;

  // one-time init: term table + zero pads (pads never overwritten afterwards)
  if (tid < 112) {
    int n = tid, t = 0;
    if (n < 98) { int dz = n / 49, r = n - dz * 49, hy = r / 7, wx = r - hy * 7; t = dz * 169 + hy * 13 + wx; }
    sT[n] = t;
  }
  for (int i = tid; i < 336; i += 256) { sQ[2352 + i] = 0; sK[2352 + i] = 0; }       // rows 98..111
  for (int i = tid; i < 224; i += 256) { sVt[(i / 14) * 136 + 98 + (i % 14)] = 0; }  // V^T cols 98..111

  f32x4 po[2][4];
#pragma unroll
  for (int a = 0; a < 2; a++)
#pragma unroll
    for (int b = 0; b < 4; b++) po[a][b] = (f32x4){0.f, 0.f, 0.f, 0.f};

  for (int hd = 0; hd < 4; hd++) {
    __syncthreads();
    long base = (long)(wi * 4 + hd) * 1568;
    const u32* qp = (const u32*)(Qg + base);
    const u32* kp = (const u32*)(Kg + base);
    const u32* vp = (const u32*)(Vg + base);
    for (int i = tid; i < 784; i += 256) {
      u32 v = qp[i];
      int n = i >> 3, j2 = (i & 7) * 2;
      *(u32*)&sQ[n * 24 + j2] = v;
    }
    for (int i = tid; i < 784; i += 256) {
      u32 v = kp[i];
      int n = i >> 3, j2 = (i & 7) * 2;
      *(u32*)&sK[n * 24 + j2] = v;
    }
    for (int i = tid; i < 784; i += 256) {
      u32 v = vp[i];
      int n = i >> 3, j2 = (i & 7) * 2;
      sVt[j2 * 136 + n] = (u16)(v & 0xffffu);
      sVt[(j2 + 1) * 136 + n] = (u16)(v >> 16);
    }
    __syncthreads();

#pragma unroll
    for (int mi = 0; mi < 2; mi++) {
      int mt = wv + mi * 4;
      if (mt > 6) continue;
      int baserow = mt * 16 + lk * 4;
      // ---- QK^T (K=16 zero-padded to 32 via lk<2 masking) ----
      s16x8 Aq = {};
      if (lk < 2) Aq = *(const s16x8*)&sQ[(mt * 16 + lm) * 24 + lk * 8];
      f32x4 S[7];
#pragma unroll
      for (int nt = 0; nt < 7; nt++) {
        s16x8 Bk = {};
        if (lk < 2) Bk = *(const s16x8*)&sK[(nt * 16 + lm) * 24 + lk * 8];
        S[nt] = __builtin_amdgcn_mfma_f32_16x16x32_bf16(Aq, Bk, (f32x4){0.f, 0.f, 0.f, 0.f}, 0, 0, 0);
      }
      // ---- bias + softmax (rows in this lane's 4 regs, cols across 16 lanes) ----
      int tr0 = sT[baserow] + 253, tr1 = sT[baserow + 1] + 253;
      int tr2 = sT[baserow + 2] + 253, tr3 = sT[baserow + 3] + 253;
      float mx0 = -3e38f, mx1 = -3e38f, mx2 = -3e38f, mx3 = -3e38f;
#pragma unroll
      for (int nt = 0; nt < 7; nt++) {
        int m = nt * 16 + lm;
        int tm = sT[m];
        bool valid = m < 98;
        float b0 = valid ? rpb[(tr0 - tm) * 4 + hd] : -1e30f;
        float b1 = valid ? rpb[(tr1 - tm) * 4 + hd] : -1e30f;
        float b2 = valid ? rpb[(tr2 - tm) * 4 + hd] : -1e30f;
        float b3 = valid ? rpb[(tr3 - tm) * 4 + hd] : -1e30f;
        S[nt][0] += b0; S[nt][1] += b1; S[nt][2] += b2; S[nt][3] += b3;
        mx0 = fmaxf(mx0, S[nt][0]); mx1 = fmaxf(mx1, S[nt][1]);
        mx2 = fmaxf(mx2, S[nt][2]); mx3 = fmaxf(mx3, S[nt][3]);
      }
#pragma unroll
      for (int off = 1; off < 16; off <<= 1) {
        mx0 = fmaxf(mx0, __shfl_xor(mx0, off));
        mx1 = fmaxf(mx1, __shfl_xor(mx1, off));
        mx2 = fmaxf(mx2, __shfl_xor(mx2, off));
        mx3 = fmaxf(mx3, __shfl_xor(mx3, off));
      }
      float s0 = 0.f, s1 = 0.f, s2 = 0.f, s3 = 0.f;
#pragma unroll
      for (int nt = 0; nt < 7; nt++) {
        S[nt][0] = __expf(S[nt][0] - mx0); s0 += S[nt][0];
        S[nt][1] = __expf(S[nt][1] - mx1); s1 += S[nt][1];
        S[nt][2] = __expf(S[nt][2] - mx2); s2 += S[nt][2];
        S[nt][3] = __expf(S[nt][3] - mx3); s3 += S[nt][3];
      }
#pragma unroll
      for (int off = 1; off < 16; off <<= 1) {
        s0 += __shfl_xor(s0, off); s1 += __shfl_xor(s1, off);
        s2 += __shfl_xor(s2, off); s3 += __shfl_xor(s3, off);
      }
      float i0 = 1.f / s0, i1 = 1.f / s1, i2 = 1.f / s2, i3 = 1.f / s3;
#pragma unroll
      for (int nt = 0; nt < 7; nt++) {
        int c = nt * 16 + lm;
        sP[(baserow + 0) * 120 + c] = f2b(S[nt][0] * i0);
        sP[(baserow + 1) * 120 + c] = f2b(S[nt][1] * i1);
        sP[(baserow + 2) * 120 + c] = f2b(S[nt][2] * i2);
        sP[(baserow + 3) * 120 + c] = f2b(S[nt][3] * i3);
      }
      // ---- PV: k=0..95 unmasked (max col 95 < 120, in-row), k=96..127 masked ----
      int rowoff = (mt * 16 + lm) * 120;
      f32x4 pv = (f32x4){0.f, 0.f, 0.f, 0.f};
#pragma unroll
      for (int ks = 0; ks < 3; ks++) {
        s16x8 Ap = *(const s16x8*)&sP[rowoff + ks * 32 + lk * 8];
        s16x8 Bv = *(const s16x8*)&sVt[lm * 136 + ks * 32 + lk * 8];
        pv = __builtin_amdgcn_mfma_f32_16x16x32_bf16(Ap, Bv, pv, 0, 0, 0);
      }
      {
        s16x8 Ap = {}, Bv = {};
        if (lk < 2) {   // matrix k 96..111 (cols 98..111 are exact zeros); k>=112 zero
          Ap = *(const s16x8*)&sP[rowoff + 96 + lk * 8];
          Bv = *(const s16x8*)&sVt[lm * 136 + 96 + lk * 8];
        }
        pv = __builtin_amdgcn_mfma_f32_16x16x32_bf16(Ap, Bv, pv, 0, 0, 0);
      }
#pragma unroll
      for (int r = 0; r < 4; r++) sO[(baserow + r) * 24 + lm] = f2b(pv[r]);
      // ---- per-head proj into po (K=16 pad 32) ----
      s16x8 Ao = {};
      if (lk < 2) Ao = *(const s16x8*)&sO[(mt * 16 + lm) * 24 + lk * 8];
#pragma unroll
      for (int nt = 0; nt < 4; nt++) {
        s16x8 Bw = {};
        if (lk < 2) Bw = *(const s16x8*)&pwb[((((hd * 4 + nt) * 2 + lk) * 16 + lm) * 8)];
        po[mi][nt] = __builtin_amdgcn_mfma_f32_16x16x32_bf16(Ao, Bw, po[mi][nt], 0, 0, 0);
      }
    }
  }
  // ---- epilogue: acc[p*64+col] += po + pb ----
  int b = wi >> 10, d0 = (wi >> 8) & 3, h0 = (wi >> 4) & 15, w0 = wi & 15;
  float pbv[4];
#pragma unroll
  for (int nt = 0; nt < 4; nt++) pbv[nt] = pb[nt * 16 + lm];
#pragma unroll
  for (int mi = 0; mi < 2; mi++) {
    int mt = wv + mi * 4;
    if (mt > 6) continue;
#pragma unroll
    for (int r = 0; r < 4; r++) {
      int n = mt * 16 + lk * 4 + r;
      if (n >= 98) continue;
      int dz = n / 49, rr = n - dz * 49, oy = rr / 7, ox = rr - oy * 7;
      long p = ((long)(b * 8 + d0 * 2 + dz) * 112 + (h0 * 7 + oy)) * 112 + (w0 * 7 + ox);
      float* ap = accg + p * 64;
#pragma unroll
      for (int nt = 0; nt < 4; nt++) {
        int col = nt * 16 + lm;
        ap[col] += po[mi][nt][r] + pbv[nt];
      }
    }
  }
}

// ---------------- Temporal attention: one wave per pixel sequence (D=8) ---------
__global__ __launch_bounds__(256) void k_tattn(const float* __restrict__ h, const float* __restrict__ qw,
    const float* __restrict__ qb, const float* __restrict__ rpbt, const float* __restrict__ pw,
    const float* __restrict__ pb, float* __restrict__ acc) {
  __shared__ float sm[4][1624];
  int wv = threadIdx.x >> 6, lane = threadIdx.x & 63;
  int s = blockIdx.x * 4 + wv;
  int b = s / 12544, rr = s - b * 12544, hy = rr / 112, wx = rr - hy * 112;
  float* xt = sm[wv];
  float* qkv = xt + 520;
  float* sp = qkv + 776;
  float* o = sp + 64;
  long pbase = ((long)b * 896 + hy) * 112 + wx;
  for (int i = lane; i < 512; i += 64) {
    int n = i >> 6, c = i & 63;
    xt[n * 65 + c] = h[(pbase + (long)n * 12544) * 64 + c];
  }
  __syncthreads();
  for (int i = lane; i < 192; i += 64) {
    int n = i / 24, c4 = (i - n * 24) * 4;
    float4 a4 = *(const float4*)(qb + c4);
    float a0 = a4.x, a1 = a4.y, a2 = a4.z, a3 = a4.w;
    const float* xr = &xt[n * 65];
    const float* wp = qw + c4;
    for (int c = 0; c < 64; c++) {
      float xv = xr[c];
      float4 w4 = *(const float4*)(wp + c * 96);
      a0 += xv * w4.x; a1 += xv * w4.y;
      a2 += xv * w4.z; a3 += xv * w4.w;
    }
    float sc = (c4 < 32) ? 0.25f : 1.f;
    int ob = n * 97 + c4;
    qkv[ob] = a0 * sc; qkv[ob + 1] = a1 * sc; qkv[ob + 2] = a2 * sc; qkv[ob + 3] = a3 * sc;
  }
  __syncthreads();
  int n8 = lane >> 3, m8 = lane & 7;
  for (int hd = 0; hd < 4; hd++) {
    float sc = 0.f;
    const float* qr = &qkv[n8 * 97 + hd * 8];
    const float* kr = &qkv[m8 * 97 + 32 + hd * 8];
#pragma unroll
    for (int e = 0; e < 8; e++) sc += qr[e] * kr[e];
    sc += rpbt[(n8 - m8 + 7) * 4 + hd];
    sp[lane] = sc;
    __syncthreads();
    if (lane < 8) {
      float* row = &sp[lane * 8];
      float mx = -1e30f;
      for (int m = 0; m < 8; m++) mx = fmaxf(mx, row[m]);
      float sum = 0.f;
      for (int m = 0; m < 8; m++) { float e = __expf(row[m] - mx); row[m] = e; sum += e; }
      float inv = 1.f / sum;
      for (int m = 0; m < 8; m++) row[m] *= inv;
    }
    __syncthreads();
    float a = 0.f;
    const float* prow = &sp[n8 * 8];
#pragma unroll
    for (int m = 0; m < 8; m++) a += prow[m] * qkv[m * 97 + 64 + hd * 8 + m8];
    o[n8 * 33 + hd * 8 + m8] = a;
    __syncthreads();
  }
  for (int i = lane; i < 128; i += 64) {
    int n = i >> 4, c4 = (i & 15) << 2;
    float4 a4 = *(const float4*)(pb + c4);
    float a0 = a4.x, a1 = a4.y, a2 = a4.z, a3 = a4.w;
    const float* orow = &o[n * 33];
    const float* wp = pw + c4;
    for (int k = 0; k < 32; k++) {
      float ov = orow[k];
      float4 w4 = *(const float4*)(wp + k * 64);
      a0 += ov * w4.x; a1 += ov * w4.y; a2 += ov * w4.z; a3 += ov * w4.w;
    }
    long ab = (pbase + (long)n * 12544) * 64 + c4;
    acc[ab] += a0; acc[ab + 1] += a1; acc[ab + 2] += a2; acc[ab + 3] += a3;
  }
}

// ---------------- Weight prepack: OIDHW f32 -> WB[kk][co][ci] bf16 --------------
__global__ __launch_bounds__(256) void k_wprep(const float* __restrict__ w0, const float* __restrict__ w1,
    const float* __restrict__ w2, const float* __restrict__ w3, u16* __restrict__ WB) {
  int c = blockIdx.y;
  int i = blockIdx.x * 256 + threadIdx.x;   // < 27648
  const float* src = c == 0 ? w0 : c == 1 ? w1 : c == 2 ? w2 : w3;
  int co = i / 864, rem = i - co * 864, ci = rem / 27, kk = rem - ci * 27;
  WB[c * 27648 + kk * 1024 + co * 32 + ci] = f2b(src[i]);
}

// ---------------- MFMA implicit-GEMM 3x3x3 conv, 32ci->32co, bf16 in, fp32 acc --
__global__ __launch_bounds__(64) void k_convm(const u16* __restrict__ in, const u16* __restrict__ wb,
    const float* __restrict__ bias, int mode,
    const float* __restrict__ hbuf, const float* __restrict__ accb,
    float* __restrict__ dout, float* __restrict__ x2f, u16* __restrict__ outb) {
  int row = blockIdx.x;
  int hh = row % 112, bz = row / 112;
  int d = bz & 7, bb = bz >> 3;
  long prow = (long)row * 112;
  int l = threadIdx.x, lm = l & 15, lk = l >> 4;
  f32x4 acc[7][2];
#pragma unroll
  for (int t = 0; t < 7; t++) { acc[t][0] = (f32x4){0.f,0.f,0.f,0.f}; acc[t][1] = (f32x4){0.f,0.f,0.f,0.f}; }
  for (int kd = 0; kd < 3; kd++) {
    int zd = d + kd - 1;
    if (zd < 0 || zd > 7) continue;
    for (int kh = 0; kh < 3; kh++) {
      int yy = hh + kh - 1;
      if (yy < 0 || yy > 111) continue;
      const u16* ip = in + ((long)((bb * 8 + zd) * 112 + yy)) * 112 * 32;
      int kkb = kd * 9 + kh * 3;
      s16x8 B0[3], B1[3];
#pragma unroll
      for (int kw = 0; kw < 3; kw++) {
        const u16* wp = wb + (kkb + kw) * 1024 + lk * 8;
        B0[kw] = *(const s16x8*)(wp + lm * 32);
        B1[kw] = *(const s16x8*)(wp + (16 + lm) * 32);
      }
#pragma unroll
      for (int t = 0; t < 7; t++) {
#pragma unroll
        for (int kw = 0; kw < 3; kw++) {
          int w = t * 16 + lm + kw - 1;
          s16x8 A = {};
          if ((unsigned)w < 112u) A = *(const s16x8*)(ip + (long)w * 32 + lk * 8);
          acc[t][0] = __builtin_amdgcn_mfma_f32_16x16x32_bf16(A, B0[kw], acc[t][0], 0, 0, 0);
          acc[t][1] = __builtin_amdgcn_mfma_f32_16x16x32_bf16(A, B1[kw], acc[t][1], 0, 0, 0);
        }
      }
    }
  }
  float b0 = bias[lm], b1 = bias[16 + lm];
#pragma unroll
  for (int t = 0; t < 7; t++) {
#pragma unroll
    for (int r = 0; r < 4; r++) {
      long pos = prow + t * 16 + lk * 4 + r;
      float v0 = acc[t][0][r] + b0;
      float v1 = acc[t][1][r] + b1;
      if (mode == 1) {
        v0 = v0 > 0.f ? v0 : 0.01f * v0;
        v1 = v1 > 0.f ? v1 : 0.01f * v1;
        outb[pos * 32 + lm] = f2b(v0);
        outb[pos * 32 + 16 + lm] = f2b(v1);
      } else if (mode == 2) {
        float y0 = v0 + hbuf[pos * 64 + lm];
        float y1v = v1 + hbuf[pos * 64 + 16 + lm];
        dout[pos * 64 + lm] = accb[pos * 64 + lm] + y0;
        dout[pos * 64 + 16 + lm] = accb[pos * 64 + 16 + lm] + y1v;
        float t0 = hbuf[pos * 64 + 32 + lm] + y0;
        float t1 = hbuf[pos * 64 + 48 + lm] + y1v;
        x2f[pos * 32 + lm] = t0;
        x2f[pos * 32 + 16 + lm] = t1;
        outb[pos * 32 + lm] = f2b(t0);
        outb[pos * 32 + 16 + lm] = f2b(t1);
      } else {
        float y0 = v0 + x2f[pos * 32 + lm];
        float y1v = v1 + x2f[pos * 32 + 16 + lm];
        dout[pos * 64 + 32 + lm] = accb[pos * 64 + 32 + lm] + y0;
        dout[pos * 64 + 48 + lm] = accb[pos * 64 + 48 + lm] + y1v;
      }
    }
  }
}

extern "C" void kernel_launch(void* const* d_in, const int* in_sizes, int n_in,
                              void* d_out, int out_size, void* d_ws, size_t ws_size,
                              hipStream_t stream) {
  const float* x        = (const float*)d_in[0];
  // d_in[1] mask_matrix: unused (all zeros; reference never applies it)
  const float* g1       = (const float*)d_in[2];
  const float* b1       = (const float*)d_in[3];
  const float* rpb_s    = (const float*)d_in[4];
  const float* qkv_w_s  = (const float*)d_in[5];
  const float* qkv_b_s  = (const float*)d_in[6];
  const float* proj_w_s = (const float*)d_in[7];
  const float* proj_b_s = (const float*)d_in[8];
  const float* rpb_t    = (const float*)d_in[9];
  const float* qkv_w_t  = (const float*)d_in[10];
  const float* qkv_b_t  = (const float*)d_in[11];
  const float* proj_w_t = (const float*)d_in[12];
  const float* proj_b_t = (const float*)d_in[13];
  const float* g2       = (const float*)d_in[14];
  const float* b2       = (const float*)d_in[15];
  const float* c1w = (const float*)d_in[16];
  const float* c1b = (const float*)d_in[17];
  const float* c2w = (const float*)d_in[18];
  const float* c2b = (const float*)d_in[19];
  const float* c3w = (const float*)d_in[20];
  const float* c3b = (const float*)d_in[21];
  const float* c4w = (const float*)d_in[22];
  const float* c4b = (const float*)d_in[23];

  // workspace (fp32 elems): acc(12.8M) | hbuf(12.8M) | creg(19.27M)
  float* acc  = (float*)d_ws;
  float* hbuf = acc + 12845056;
  float* creg = hbuf + 12845056;
  u16* Qg = (u16*)creg;
  u16* Kg = Qg + 12845056;
  u16* Vg = Kg + 12845056;
  u16* x1b = (u16*)creg;               // conv phase
  u16* t_b = x1b + 6422528;
  u16* x2b = t_b + 6422528;
  float* x2f = (float*)(x2b + 6422528);
  u16* WB = (u16*)(x2f + 6422528);
  float* dout = (float*)d_out;
  u16* pwb = (u16*)d_out;              // 8KB scratch; dead until conv2 overwrites

  // 1. LN1: h = LN(x); acc = x
  k_ln<<<50176, 256, 0, stream>>>(x, g1, b1, hbuf, acc, nullptr);
  // 2. spatial qkv (dense GEMM) -> bf16 windowed Q/K/V
  k_qkvs<<<6272, 256, 0, stream>>>(hbuf, qkv_w_s, qkv_b_s, Qg, Kg, Vg);
  // 3. proj-weight prepack into d_out scratch
  k_pwprep<<<16, 256, 0, stream>>>(proj_w_s, pwb);
  // 4. MFMA spatial attention + fused projection, acc +=
  k_sattn3<<<2048, 256, 0, stream>>>(Qg, Kg, Vg, rpb_s, pwb, proj_b_s, acc);
  // 5. temporal attention, add into acc
  k_tattn<<<6272, 256, 0, stream>>>(hbuf, qkv_w_t, qkv_b_t, rpb_t, proj_w_t, proj_b_t, acc);
  // 6. conv weight prepack (overlaps Vg; after attention)
  k_wprep<<<dim3(108, 4), 256, 0, stream>>>(c1w, c2w, c3w, c4w, WB);
  // 7. LN2: h2 = LN(acc) -> hbuf f32 + x1b bf16 (ch 0..31)
  k_ln<<<50176, 256, 0, stream>>>(acc, g2, b2, hbuf, nullptr, x1b);
  // 8. conv path 1: t = lrelu(conv(x1)) -> t_b bf16
  k_convm<<<1792, 64, 0, stream>>>(x1b, WB, c1b, 1, nullptr, nullptr, nullptr, nullptr, t_b);
  // 9. conv2 + fused: y1 = x1 + conv(t); dout(ch0..31)=acc+y1; x2f/x2b = h2[32:]+y1
  k_convm<<<1792, 64, 0, stream>>>(t_b, WB + 27648, c2b, 2, hbuf, acc, dout, x2f, x2b);
  // 10. conv path 2: t = lrelu(conv(x2b)) -> t_b bf16
  k_convm<<<1792, 64, 0, stream>>>(x2b, WB + 2 * 27648, c3b, 1, nullptr, nullptr, nullptr, nullptr, t_b);
  // 11. conv4 + fused: y2 = x2 + conv(t); dout(ch32..63) = acc + y2
  k_convm<<<1792, 64, 0, stream>>>(t_b, WB + 3 * 27648, c4b, 4, nullptr, acc, dout, x2f, nullptr);
}

// Round 10
// 567.798 us; speedup vs baseline: 8.0874x; 1.2440x over previous
//
#include <hip/hip_runtime.h>
#include <hip/hip_bf16.h>

typedef unsigned short u16;
typedef unsigned int u32;
typedef __attribute__((ext_vector_type(8))) short s16x8;
typedef __attribute__((ext_vector_type(4))) float f32x4;

__device__ __forceinline__ u16 f2b(float v) {
  u32 bits = __float_as_uint(v);
  bits += 0x7fffu + ((bits >> 16) & 1u);
  return (u16)(bits >> 16);
}
__device__ __forceinline__ float b2f(u16 u) { return __uint_as_float(((u32)u) << 16); }
__device__ __forceinline__ float bflo(u32 w) { return __uint_as_float(w << 16); }
__device__ __forceinline__ float bfhi(u32 w) { return __uint_as_float(w & 0xffff0000u); }

// ---------------- LayerNorm: writes h (f32), optionally acc=x, optionally bf16 ch0..31
__global__ __launch_bounds__(256) void k_ln(const float* __restrict__ x, const float* __restrict__ g,
    const float* __restrict__ b, float* __restrict__ hout, float* __restrict__ acc, u16* __restrict__ xb) {
  int token = blockIdx.x * 4 + (threadIdx.x >> 6);
  int lane = threadIdx.x & 63;
  long base = (long)token * 64 + lane;
  float v = x[base];
  float s = v;
#pragma unroll
  for (int o = 32; o; o >>= 1) s += __shfl_xor(s, o);
  float m = s * 0.015625f;
  float d = v - m;
  float q = d * d;
#pragma unroll
  for (int o = 32; o; o >>= 1) q += __shfl_xor(q, o);
  float r = rsqrtf(q * 0.015625f + 1e-5f);
  float hv = d * r * g[lane] + b[lane];
  hout[base] = hv;
  if (acc) acc[base] = v;
  if (xb && lane < 32) xb[(long)token * 32 + lane] = f2b(hv);
}

// ---------------- Spatial qkv: dense GEMM, h read once, bf16 windowed output ----
__global__ __launch_bounds__(256) void k_qkvs(const float* __restrict__ h, const float* __restrict__ qw,
    const float* __restrict__ qb, u16* __restrict__ Qg, u16* __restrict__ Kg, u16* __restrict__ Vg) {
  __shared__ float sx[4][512];
  int wv = threadIdx.x >> 6, lane = threadIdx.x & 63;
  long t0 = (long)blockIdx.x * 32 + wv * 8;
  for (int i = lane; i < 512; i += 64) sx[wv][i] = h[t0 * 64 + i];
  __syncthreads();
  float aq[8], ak[8], av[8];
  float bq = qb[lane], bk = qb[64 + lane], bv = qb[128 + lane];
#pragma unroll
  for (int i = 0; i < 8; i++) { aq[i] = bq; ak[i] = bk; av[i] = bv; }
  for (int k = 0; k < 64; k++) {
    float wq = qw[k * 192 + lane];
    float wk = qw[k * 192 + 64 + lane];
    float wvv = qw[k * 192 + 128 + lane];
#pragma unroll
    for (int i = 0; i < 8; i++) {
      float xv = sx[wv][i * 64 + k];
      aq[i] += xv * wq; ak[i] += xv * wk; av[i] += xv * wvv;
    }
  }
  int hd = lane >> 4, j = lane & 15;
#pragma unroll
  for (int i = 0; i < 8; i++) {
    long p = t0 + i;
    int b = (int)(p / 100352); int r = (int)(p - (long)b * 100352);
    int d = r / 12544; int r2 = r - d * 12544;
    int hy = r2 / 112, wx = r2 - hy * 112;
    int d0 = d >> 1, dz = d & 1, h0 = hy / 7, oy = hy - h0 * 7, w0 = wx / 7, ox = wx - w0 * 7;
    int wi = ((b * 4 + d0) * 16 + h0) * 16 + w0;
    int n = dz * 49 + oy * 7 + ox;
    long o = (long)(wi * 4 + hd) * 1568 + n * 16 + j;
    Qg[o] = f2b(aq[i] * 0.25f);
    Kg[o] = f2b(ak[i]);
    Vg[o] = f2b(av[i]);
  }
}

// ---------------- proj weight prepack to B-frag layout (global scratch) ---------
__global__ __launch_bounds__(256) void k_pwprep(const float* __restrict__ pw, u16* __restrict__ pwb) {
  int i = blockIdx.x * 256 + threadIdx.x;   // < 4096
  int r = i & 7, q = i >> 3;
  int col = q & 15; q >>= 4;
  int lk = q & 1; q >>= 1;
  int nt = q & 3, hd = q >> 2;
  pwb[i] = f2b(pw[(hd * 16 + lk * 8 + r) * 64 + nt * 16 + col]);
}

// ---------------- temporal qkv weight prepack to B-frag layout ------------------
// twb[((nt*2+ks)*16 + lm)*32 + kk] = qw_t[(ks*32+kk)*96 + nt*16+lm]
__global__ __launch_bounds__(256) void k_twprep(const float* __restrict__ qw, u16* __restrict__ twb) {
  int i = blockIdx.x * 256 + threadIdx.x;   // < 6144
  int kk = i & 31, q = i >> 5;
  int lm = q & 15, ksnt = q >> 4;
  int ks = ksnt & 1, nt = ksnt >> 1;
  twb[i] = f2b(qw[(ks * 32 + kk) * 96 + nt * 16 + lm]);
}

// ---------------- MFMA spatial attention + fused projection: 1 block per window -
__global__ __launch_bounds__(256) void k_sattn3(const u16* __restrict__ Qg, const u16* __restrict__ Kg,
    const u16* __restrict__ Vg, const float* __restrict__ rpb, const u16* __restrict__ pwb,
    const float* __restrict__ pb, float* __restrict__ accg) {
  __shared__ __align__(16) u16 sQ[112 * 24];
  __shared__ __align__(16) u16 sK[112 * 24];
  __shared__ __align__(16) u16 sVt[16 * 136];
  __shared__ __align__(16) u16 sP[112 * 120 + 32];
  __shared__ __align__(16) u16 sO[112 * 24];
  __shared__ int sT[112];
  int tid = threadIdx.x;
  int wi = blockIdx.x;
  int l = tid & 63, wv = tid >> 6;
  int lm = l & 15, lk = l >> 4;

  if (tid < 112) {
    int n = tid, t = 0;
    if (n < 98) { int dz = n / 49, r = n - dz * 49, hy = r / 7, wx = r - hy * 7; t = dz * 169 + hy * 13 + wx; }
    sT[n] = t;
  }
  for (int i = tid; i < 336; i += 256) { sQ[2352 + i] = 0; sK[2352 + i] = 0; }       // rows 98..111
  for (int i = tid; i < 224; i += 256) { sVt[(i / 14) * 136 + 98 + (i % 14)] = 0; }  // V^T cols 98..111

  f32x4 po[2][4];
#pragma unroll
  for (int a = 0; a < 2; a++)
#pragma unroll
    for (int b = 0; b < 4; b++) po[a][b] = (f32x4){0.f, 0.f, 0.f, 0.f};

  for (int hd = 0; hd < 4; hd++) {
    __syncthreads();
    long base = (long)(wi * 4 + hd) * 1568;
    const u32* qp = (const u32*)(Qg + base);
    const u32* kp = (const u32*)(Kg + base);
    const u32* vp = (const u32*)(Vg + base);
    for (int i = tid; i < 784; i += 256) {
      u32 v = qp[i];
      int n = i >> 3, j2 = (i & 7) * 2;
      *(u32*)&sQ[n * 24 + j2] = v;
    }
    for (int i = tid; i < 784; i += 256) {
      u32 v = kp[i];
      int n = i >> 3, j2 = (i & 7) * 2;
      *(u32*)&sK[n * 24 + j2] = v;
    }
    for (int i = tid; i < 784; i += 256) {
      u32 v = vp[i];
      int n = i >> 3, j2 = (i & 7) * 2;
      sVt[j2 * 136 + n] = (u16)(v & 0xffffu);
      sVt[(j2 + 1) * 136 + n] = (u16)(v >> 16);
    }
    __syncthreads();

#pragma unroll
    for (int mi = 0; mi < 2; mi++) {
      int mt = wv + mi * 4;
      if (mt > 6) continue;
      int baserow = mt * 16 + lk * 4;
      s16x8 Aq = {};
      if (lk < 2) Aq = *(const s16x8*)&sQ[(mt * 16 + lm) * 24 + lk * 8];
      f32x4 S[7];
#pragma unroll
      for (int nt = 0; nt < 7; nt++) {
        s16x8 Bk = {};
        if (lk < 2) Bk = *(const s16x8*)&sK[(nt * 16 + lm) * 24 + lk * 8];
        S[nt] = __builtin_amdgcn_mfma_f32_16x16x32_bf16(Aq, Bk, (f32x4){0.f, 0.f, 0.f, 0.f}, 0, 0, 0);
      }
      int tr0 = sT[baserow] + 253, tr1 = sT[baserow + 1] + 253;
      int tr2 = sT[baserow + 2] + 253, tr3 = sT[baserow + 3] + 253;
      float mx0 = -3e38f, mx1 = -3e38f, mx2 = -3e38f, mx3 = -3e38f;
#pragma unroll
      for (int nt = 0; nt < 7; nt++) {
        int m = nt * 16 + lm;
        int tm = sT[m];
        bool valid = m < 98;
        float b0 = valid ? rpb[(tr0 - tm) * 4 + hd] : -1e30f;
        float b1 = valid ? rpb[(tr1 - tm) * 4 + hd] : -1e30f;
        float b2 = valid ? rpb[(tr2 - tm) * 4 + hd] : -1e30f;
        float b3 = valid ? rpb[(tr3 - tm) * 4 + hd] : -1e30f;
        S[nt][0] += b0; S[nt][1] += b1; S[nt][2] += b2; S[nt][3] += b3;
        mx0 = fmaxf(mx0, S[nt][0]); mx1 = fmaxf(mx1, S[nt][1]);
        mx2 = fmaxf(mx2, S[nt][2]); mx3 = fmaxf(mx3, S[nt][3]);
      }
#pragma unroll
      for (int off = 1; off < 16; off <<= 1) {
        mx0 = fmaxf(mx0, __shfl_xor(mx0, off));
        mx1 = fmaxf(mx1, __shfl_xor(mx1, off));
        mx2 = fmaxf(mx2, __shfl_xor(mx2, off));
        mx3 = fmaxf(mx3, __shfl_xor(mx3, off));
      }
      float s0 = 0.f, s1 = 0.f, s2 = 0.f, s3 = 0.f;
#pragma unroll
      for (int nt = 0; nt < 7; nt++) {
        S[nt][0] = __expf(S[nt][0] - mx0); s0 += S[nt][0];
        S[nt][1] = __expf(S[nt][1] - mx1); s1 += S[nt][1];
        S[nt][2] = __expf(S[nt][2] - mx2); s2 += S[nt][2];
        S[nt][3] = __expf(S[nt][3] - mx3); s3 += S[nt][3];
      }
#pragma unroll
      for (int off = 1; off < 16; off <<= 1) {
        s0 += __shfl_xor(s0, off); s1 += __shfl_xor(s1, off);
        s2 += __shfl_xor(s2, off); s3 += __shfl_xor(s3, off);
      }
      float i0 = 1.f / s0, i1 = 1.f / s1, i2 = 1.f / s2, i3 = 1.f / s3;
#pragma unroll
      for (int nt = 0; nt < 7; nt++) {
        int c = nt * 16 + lm;
        sP[(baserow + 0) * 120 + c] = f2b(S[nt][0] * i0);
        sP[(baserow + 1) * 120 + c] = f2b(S[nt][1] * i1);
        sP[(baserow + 2) * 120 + c] = f2b(S[nt][2] * i2);
        sP[(baserow + 3) * 120 + c] = f2b(S[nt][3] * i3);
      }
      int rowoff = (mt * 16 + lm) * 120;
      f32x4 pv = (f32x4){0.f, 0.f, 0.f, 0.f};
#pragma unroll
      for (int ks = 0; ks < 3; ks++) {
        s16x8 Ap = *(const s16x8*)&sP[rowoff + ks * 32 + lk * 8];
        s16x8 Bv = *(const s16x8*)&sVt[lm * 136 + ks * 32 + lk * 8];
        pv = __builtin_amdgcn_mfma_f32_16x16x32_bf16(Ap, Bv, pv, 0, 0, 0);
      }
      {
        s16x8 Ap = {}, Bv = {};
        if (lk < 2) {
          Ap = *(const s16x8*)&sP[rowoff + 96 + lk * 8];
          Bv = *(const s16x8*)&sVt[lm * 136 + 96 + lk * 8];
        }
        pv = __builtin_amdgcn_mfma_f32_16x16x32_bf16(Ap, Bv, pv, 0, 0, 0);
      }
#pragma unroll
      for (int r = 0; r < 4; r++) sO[(baserow + r) * 24 + lm] = f2b(pv[r]);
      s16x8 Ao = {};
      if (lk < 2) Ao = *(const s16x8*)&sO[(mt * 16 + lm) * 24 + lk * 8];
#pragma unroll
      for (int nt = 0; nt < 4; nt++) {
        s16x8 Bw = {};
        if (lk < 2) Bw = *(const s16x8*)&pwb[((((hd * 4 + nt) * 2 + lk) * 16 + lm) * 8)];
        po[mi][nt] = __builtin_amdgcn_mfma_f32_16x16x32_bf16(Ao, Bw, po[mi][nt], 0, 0, 0);
      }
    }
  }
  int b = wi >> 10, d0 = (wi >> 8) & 3, h0 = (wi >> 4) & 15, w0 = wi & 15;
  float pbv[4];
#pragma unroll
  for (int nt = 0; nt < 4; nt++) pbv[nt] = pb[nt * 16 + lm];
#pragma unroll
  for (int mi = 0; mi < 2; mi++) {
    int mt = wv + mi * 4;
    if (mt > 6) continue;
#pragma unroll
    for (int r = 0; r < 4; r++) {
      int n = mt * 16 + lk * 4 + r;
      if (n >= 98) continue;
      int dz = n / 49, rr = n - dz * 49, oy = rr / 7, ox = rr - oy * 7;
      long p = ((long)(b * 8 + d0 * 2 + dz) * 112 + (h0 * 7 + oy)) * 112 + (w0 * 7 + ox);
      float* ap = accg + p * 64;
#pragma unroll
      for (int nt = 0; nt < 4; nt++) {
        int col = nt * 16 + lm;
        ap[col] += po[mi][nt][r] + pbv[nt];
      }
    }
  }
}

// ---------------- Temporal qkv: MFMA dense GEMM M=200704 N=96 K=64 --------------
// 4 waves x 16 tokens; writes bf16 T[(seq*8+d)*96+ch], q-cols scaled by 0.25
__global__ __launch_bounds__(256) void k_qkvt(const float* __restrict__ h, const u16* __restrict__ twb,
    const float* __restrict__ qb, u16* __restrict__ T) {
  int l = threadIdx.x & 63, wv = threadIdx.x >> 6;
  int lm = l & 15, lk = l >> 4;
  long t0 = (long)blockIdx.x * 64 + wv * 16;
  const float* hp = h + (t0 + lm) * 64;
  s16x8 A[2];
#pragma unroll
  for (int ks = 0; ks < 2; ks++) {
    float4 x0 = *(const float4*)(hp + ks * 32 + lk * 8);
    float4 x1 = *(const float4*)(hp + ks * 32 + lk * 8 + 4);
    s16x8 a;
    a[0] = (short)f2b(x0.x); a[1] = (short)f2b(x0.y); a[2] = (short)f2b(x0.z); a[3] = (short)f2b(x0.w);
    a[4] = (short)f2b(x1.x); a[5] = (short)f2b(x1.y); a[6] = (short)f2b(x1.z); a[7] = (short)f2b(x1.w);
    A[ks] = a;
  }
  f32x4 C[6];
#pragma unroll
  for (int nt = 0; nt < 6; nt++) C[nt] = (f32x4){0.f, 0.f, 0.f, 0.f};
#pragma unroll
  for (int ks = 0; ks < 2; ks++) {
#pragma unroll
    for (int nt = 0; nt < 6; nt++) {
      s16x8 B = *(const s16x8*)&twb[((nt * 2 + ks) * 16 + lm) * 32 + lk * 8];
      C[nt] = __builtin_amdgcn_mfma_f32_16x16x32_bf16(A[ks], B, C[nt], 0, 0, 0);
    }
  }
  float qbv[6];
#pragma unroll
  for (int nt = 0; nt < 6; nt++) qbv[nt] = qb[nt * 16 + lm];
#pragma unroll
  for (int r = 0; r < 4; r++) {
    long t = t0 + lk * 4 + r;
    int bb = (int)(t / 100352); int r1 = (int)(t - (long)bb * 100352);
    int d = r1 / 12544; int rr = r1 - d * 12544;
    long sidx = ((long)(bb * 12544 + rr) * 8 + d) * 96;
#pragma unroll
    for (int nt = 0; nt < 6; nt++) {
      int ch = nt * 16 + lm;
      float v = C[nt][r] + qbv[nt];
      if (nt < 2) v *= 0.25f;
      T[sidx + ch] = f2b(v);
    }
  }
}

// ---------------- Temporal attention (per pixel-seq, D=8) + proj, acc += --------
__global__ __launch_bounds__(256) void k_tattn2(const u16* __restrict__ T, const float* __restrict__ rpbt,
    const float* __restrict__ pw, const float* __restrict__ pb, float* __restrict__ acc) {
  __shared__ float sm[4][1064];   // sq 8x100, o 8x33
  int wv = threadIdx.x >> 6, lane = threadIdx.x & 63;
  int s = blockIdx.x * 4 + wv;
  int b = s / 12544, rr = s - b * 12544;
  float* sq = sm[wv];
  float* o = sq + 800;
  const u32* Tp = (const u32*)(T + (long)s * 768);
  for (int i = lane; i < 192; i += 64) {
    u32 lo = Tp[i * 2], hi = Tp[i * 2 + 1];
    int d = i / 24, base = (i - d * 24) * 4;
    float* dst = sq + d * 100 + base;
    dst[0] = bflo(lo); dst[1] = bfhi(lo); dst[2] = bflo(hi); dst[3] = bfhi(hi);
  }
  __syncthreads();
  if (lane < 32) {
    int hd = lane >> 3, n = lane & 7;
    const float* qr = sq + n * 100 + hd * 8;
    float p[8];
    float mx = -3e38f;
#pragma unroll
    for (int m = 0; m < 8; m++) {
      const float* kr = sq + m * 100 + 32 + hd * 8;
      float sc = 0.f;
#pragma unroll
      for (int e = 0; e < 8; e++) sc += qr[e] * kr[e];
      sc += rpbt[(n - m + 7) * 4 + hd];
      p[m] = sc; mx = fmaxf(mx, sc);
    }
    float sum = 0.f;
#pragma unroll
    for (int m = 0; m < 8; m++) { p[m] = __expf(p[m] - mx); sum += p[m]; }
    float inv = 1.f / sum;
#pragma unroll
    for (int j = 0; j < 8; j++) {
      float oj = 0.f;
#pragma unroll
      for (int m = 0; m < 8; m++) oj += p[m] * sq[m * 100 + 64 + hd * 8 + j];
      o[n * 33 + hd * 8 + j] = oj * inv;
    }
  }
  __syncthreads();
  float a[8];
  float pbc = pb[lane];
#pragma unroll
  for (int n = 0; n < 8; n++) a[n] = pbc;
  for (int k = 0; k < 32; k++) {
    float w = pw[k * 64 + lane];
#pragma unroll
    for (int n = 0; n < 8; n++) a[n] += o[n * 33 + k] * w;
  }
  long base = ((long)b * 100352 + rr) * 64 + lane;
#pragma unroll
  for (int n = 0; n < 8; n++) acc[base + (long)n * 802816] += a[n];
}

// ---------------- Weight prepack: OIDHW f32 -> WB[kk][co][ci] bf16 --------------
__global__ __launch_bounds__(256) void k_wprep(const float* __restrict__ w0, const float* __restrict__ w1,
    const float* __restrict__ w2, const float* __restrict__ w3, u16* __restrict__ WB) {
  int c = blockIdx.y;
  int i = blockIdx.x * 256 + threadIdx.x;   // < 27648
  const float* src = c == 0 ? w0 : c == 1 ? w1 : c == 2 ? w2 : w3;
  int co = i / 864, rem = i - co * 864, ci = rem / 27, kk = rem - ci * 27;
  WB[c * 27648 + kk * 1024 + co * 32 + ci] = f2b(src[i]);
}

// ---------------- MFMA implicit-GEMM 3x3x3 conv, 32ci->32co, bf16 in, fp32 acc --
__global__ __launch_bounds__(64) void k_convm(const u16* __restrict__ in, const u16* __restrict__ wb,
    const float* __restrict__ bias, int mode,
    const float* __restrict__ hbuf, const float* __restrict__ accb,
    float* __restrict__ dout, float* __restrict__ x2f, u16* __restrict__ outb) {
  int row = blockIdx.x;
  int hh = row % 112, bz = row / 112;
  int d = bz & 7, bb = bz >> 3;
  long prow = (long)row * 112;
  int l = threadIdx.x, lm = l & 15, lk = l >> 4;
  f32x4 acc[7][2];
#pragma unroll
  for (int t = 0; t < 7; t++) { acc[t][0] = (f32x4){0.f,0.f,0.f,0.f}; acc[t][1] = (f32x4){0.f,0.f,0.f,0.f}; }
  for (int kd = 0; kd < 3; kd++) {
    int zd = d + kd - 1;
    if (zd < 0 || zd > 7) continue;
    for (int kh = 0; kh < 3; kh++) {
      int yy = hh + kh - 1;
      if (yy < 0 || yy > 111) continue;
      const u16* ip = in + ((long)((bb * 8 + zd) * 112 + yy)) * 112 * 32;
      int kkb = kd * 9 + kh * 3;
      s16x8 B0[3], B1[3];
#pragma unroll
      for (int kw = 0; kw < 3; kw++) {
        const u16* wp = wb + (kkb + kw) * 1024 + lk * 8;
        B0[kw] = *(const s16x8*)(wp + lm * 32);
        B1[kw] = *(const s16x8*)(wp + (16 + lm) * 32);
      }
#pragma unroll
      for (int t = 0; t < 7; t++) {
#pragma unroll
        for (int kw = 0; kw < 3; kw++) {
          int w = t * 16 + lm + kw - 1;
          s16x8 A = {};
          if ((unsigned)w < 112u) A = *(const s16x8*)(ip + (long)w * 32 + lk * 8);
          acc[t][0] = __builtin_amdgcn_mfma_f32_16x16x32_bf16(A, B0[kw], acc[t][0], 0, 0, 0);
          acc[t][1] = __builtin_amdgcn_mfma_f32_16x16x32_bf16(A, B1[kw], acc[t][1], 0, 0, 0);
        }
      }
    }
  }
  float b0 = bias[lm], b1 = bias[16 + lm];
#pragma unroll
  for (int t = 0; t < 7; t++) {
#pragma unroll
    for (int r = 0; r < 4; r++) {
      long pos = prow + t * 16 + lk * 4 + r;
      float v0 = acc[t][0][r] + b0;
      float v1 = acc[t][1][r] + b1;
      if (mode == 1) {
        v0 = v0 > 0.f ? v0 : 0.01f * v0;
        v1 = v1 > 0.f ? v1 : 0.01f * v1;
        outb[pos * 32 + lm] = f2b(v0);
        outb[pos * 32 + 16 + lm] = f2b(v1);
      } else if (mode == 2) {
        float y0 = v0 + hbuf[pos * 64 + lm];
        float y1v = v1 + hbuf[pos * 64 + 16 + lm];
        dout[pos * 64 + lm] = accb[pos * 64 + lm] + y0;
        dout[pos * 64 + 16 + lm] = accb[pos * 64 + 16 + lm] + y1v;
        float t0 = hbuf[pos * 64 + 32 + lm] + y0;
        float t1 = hbuf[pos * 64 + 48 + lm] + y1v;
        x2f[pos * 32 + lm] = t0;
        x2f[pos * 32 + 16 + lm] = t1;
        outb[pos * 32 + lm] = f2b(t0);
        outb[pos * 32 + 16 + lm] = f2b(t1);
      } else {
        float y0 = v0 + x2f[pos * 32 + lm];
        float y1v = v1 + x2f[pos * 32 + 16 + lm];
        dout[pos * 64 + 32 + lm] = accb[pos * 64 + 32 + lm] + y0;
        dout[pos * 64 + 48 + lm] = accb[pos * 64 + 48 + lm] + y1v;
      }
    }
  }
}

extern "C" void kernel_launch(void* const* d_in, const int* in_sizes, int n_in,
                              void* d_out, int out_size, void* d_ws, size_t ws_size,
                              hipStream_t stream) {
  const float* x        = (const float*)d_in[0];
  // d_in[1] mask_matrix: unused (all zeros; reference never applies it)
  const float* g1       = (const float*)d_in[2];
  const float* b1       = (const float*)d_in[3];
  const float* rpb_s    = (const float*)d_in[4];
  const float* qkv_w_s  = (const float*)d_in[5];
  const float* qkv_b_s  = (const float*)d_in[6];
  const float* proj_w_s = (const float*)d_in[7];
  const float* proj_b_s = (const float*)d_in[8];
  const float* rpb_t    = (const float*)d_in[9];
  const float* qkv_w_t  = (const float*)d_in[10];
  const float* qkv_b_t  = (const float*)d_in[11];
  const float* proj_w_t = (const float*)d_in[12];
  const float* proj_b_t = (const float*)d_in[13];
  const float* g2       = (const float*)d_in[14];
  const float* b2       = (const float*)d_in[15];
  const float* c1w = (const float*)d_in[16];
  const float* c1b = (const float*)d_in[17];
  const float* c2w = (const float*)d_in[18];
  const float* c2b = (const float*)d_in[19];
  const float* c3w = (const float*)d_in[20];
  const float* c3b = (const float*)d_in[21];
  const float* c4w = (const float*)d_in[22];
  const float* c4b = (const float*)d_in[23];

  // workspace (fp32 elems): acc(12.8M) | hbuf(12.8M) | creg(19.27M)
  float* acc  = (float*)d_ws;
  float* hbuf = acc + 12845056;
  float* creg = hbuf + 12845056;
  u16* Qg = (u16*)creg;
  u16* Kg = Qg + 12845056;
  u16* Vg = Kg + 12845056;
  u16* Tt = (u16*)creg;                // temporal qkv (19.27M u16), after sattn3
  u16* x1b = (u16*)creg;               // conv phase
  u16* t_b = x1b + 6422528;
  u16* x2b = t_b + 6422528;
  float* x2f = (float*)(x2b + 6422528);
  u16* WB = (u16*)(x2f + 6422528);
  float* dout = (float*)d_out;
  u16* pwb = (u16*)d_out;              // scratch in d_out; dead before conv2 writes
  u16* twb = (u16*)d_out + 4096;       // 12KB more scratch

  // 1. LN1: h = LN(x); acc = x
  k_ln<<<50176, 256, 0, stream>>>(x, g1, b1, hbuf, acc, nullptr);
  // 2. spatial qkv (dense GEMM) -> bf16 windowed Q/K/V
  k_qkvs<<<6272, 256, 0, stream>>>(hbuf, qkv_w_s, qkv_b_s, Qg, Kg, Vg);
  // 3. weight prepacks into d_out scratch
  k_pwprep<<<16, 256, 0, stream>>>(proj_w_s, pwb);
  k_twprep<<<24, 256, 0, stream>>>(qkv_w_t, twb);
  // 4. MFMA spatial attention + fused projection, acc +=
  k_sattn3<<<2048, 256, 0, stream>>>(Qg, Kg, Vg, rpb_s, pwb, proj_b_s, acc);
  // 5. temporal qkv (MFMA dense) -> Tt (overlaps dead Qg/Kg)
  k_qkvt<<<3136, 256, 0, stream>>>(hbuf, twb, qkv_b_t, Tt);
  // 6. temporal attention + proj, acc +=
  k_tattn2<<<6272, 256, 0, stream>>>(Tt, rpb_t, proj_w_t, proj_b_t, acc);
  // 7. conv weight prepack
  k_wprep<<<dim3(108, 4), 256, 0, stream>>>(c1w, c2w, c3w, c4w, WB);
  // 8. LN2: h2 = LN(acc) -> hbuf f32 + x1b bf16 (ch 0..31)
  k_ln<<<50176, 256, 0, stream>>>(acc, g2, b2, hbuf, nullptr, x1b);
  // 9. conv path 1: t = lrelu(conv(x1)) -> t_b bf16
  k_convm<<<1792, 64, 0, stream>>>(x1b, WB, c1b, 1, nullptr, nullptr, nullptr, nullptr, t_b);
  // 10. conv2 + fused: y1 = x1 + conv(t); dout(ch0..31)=acc+y1; x2f/x2b = h2[32:]+y1
  k_convm<<<1792, 64, 0, stream>>>(t_b, WB + 27648, c2b, 2, hbuf, acc, dout, x2f, x2b);
  // 11. conv path 2: t = lrelu(conv(x2b)) -> t_b bf16
  k_convm<<<1792, 64, 0, stream>>>(x2b, WB + 2 * 27648, c3b, 1, nullptr, nullptr, nullptr, nullptr, t_b);
  // 12. conv4 + fused: y2 = x2 + conv(t); dout(ch32..63) = acc + y2
  k_convm<<<1792, 64, 0, stream>>>(t_b, WB + 3 * 27648, c4b, 4, nullptr, acc, dout, x2f, nullptr);
}

// Round 11
// 465.142 us; speedup vs baseline: 9.8723x; 1.2207x over previous
//
#include <hip/hip_runtime.h>
#include <hip/hip_bf16.h>

typedef unsigned short u16;
typedef unsigned int u32;
typedef __attribute__((ext_vector_type(8))) short s16x8;
typedef __attribute__((ext_vector_type(4))) float f32x4;

__device__ __forceinline__ u16 f2b(float v) {
  u32 bits = __float_as_uint(v);
  bits += 0x7fffu + ((bits >> 16) & 1u);
  return (u16)(bits >> 16);
}
__device__ __forceinline__ float b2f(u16 u) { return __uint_as_float(((u32)u) << 16); }
__device__ __forceinline__ float bflo(u32 w) { return __uint_as_float(w << 16); }
__device__ __forceinline__ float bfhi(u32 w) { return __uint_as_float(w & 0xffff0000u); }

// ---------------- LayerNorm: writes h (f32), optionally acc=x, optionally bf16 ch0..31
__global__ __launch_bounds__(256) void k_ln(const float* __restrict__ x, const float* __restrict__ g,
    const float* __restrict__ b, float* __restrict__ hout, float* __restrict__ acc, u16* __restrict__ xb) {
  int token = blockIdx.x * 4 + (threadIdx.x >> 6);
  int lane = threadIdx.x & 63;
  long base = (long)token * 64 + lane;
  float v = x[base];
  float s = v;
#pragma unroll
  for (int o = 32; o; o >>= 1) s += __shfl_xor(s, o);
  float m = s * 0.015625f;
  float d = v - m;
  float q = d * d;
#pragma unroll
  for (int o = 32; o; o >>= 1) q += __shfl_xor(q, o);
  float r = rsqrtf(q * 0.015625f + 1e-5f);
  float hv = d * r * g[lane] + b[lane];
  hout[base] = hv;
  if (acc) acc[base] = v;
  if (xb && lane < 32) xb[(long)token * 32 + lane] = f2b(hv);
}

// ---------------- spatial qkv weight prepack (N=192) to B-frag layout -----------
__global__ __launch_bounds__(256) void k_swprep(const float* __restrict__ qw, u16* __restrict__ swb) {
  int i = blockIdx.x * 256 + threadIdx.x;   // < 12288
  int kk = i & 31, q = i >> 5;
  int lm = q & 15, ksnt = q >> 4;           // ksnt = nt*2+ks < 24
  int ks = ksnt & 1, nt = ksnt >> 1;
  swb[i] = f2b(qw[(ks * 32 + kk) * 192 + nt * 16 + lm]);
}

// ---------------- temporal qkv weight prepack (N=96) to B-frag layout -----------
__global__ __launch_bounds__(256) void k_twprep(const float* __restrict__ qw, u16* __restrict__ twb) {
  int i = blockIdx.x * 256 + threadIdx.x;   // < 6144
  int kk = i & 31, q = i >> 5;
  int lm = q & 15, ksnt = q >> 4;
  int ks = ksnt & 1, nt = ksnt >> 1;
  twb[i] = f2b(qw[(ks * 32 + kk) * 96 + nt * 16 + lm]);
}

// ---------------- proj weight prepack to B-frag layout --------------------------
__global__ __launch_bounds__(256) void k_pwprep(const float* __restrict__ pw, u16* __restrict__ pwb) {
  int i = blockIdx.x * 256 + threadIdx.x;   // < 4096
  int r = i & 7, q = i >> 3;
  int col = q & 15; q >>= 4;
  int lk = q & 1; q >>= 1;
  int nt = q & 3, hd = q >> 2;
  pwb[i] = f2b(pw[(hd * 16 + lk * 8 + r) * 64 + nt * 16 + col]);
}

// ---------------- rel-pos bias table: Bt[hd][n][m], pads = -1e30 ----------------
__global__ __launch_bounds__(256) void k_bprep(const float* __restrict__ rpb, float* __restrict__ Bt) {
  int i = blockIdx.x * 256 + threadIdx.x;   // grid 196 -> 50176 exact
  int m = i % 112, q = i / 112;
  int n = q % 112, hd = q / 112;
  float v = -1e30f;
  if (n < 98 && m < 98) {
    int dzn = n / 49, rn = n % 49, hyn = rn / 7, wxn = rn % 7;
    int dzm = m / 49, rm = m % 49, hym = rm / 7, wxm = rm % 7;
    int idx = (dzn - dzm + 1) * 169 + (hyn - hym + 6) * 13 + (wxn - wxm + 6);
    v = rpb[idx * 4 + hd];
  }
  Bt[i] = v;
}

// ---------------- Spatial qkv: MFMA GEMM M=200704 N=192 K=64 --------------------
// clone of verified k_qkvt; writes bf16 windowed Q/K/V (Q scaled 0.25)
__global__ __launch_bounds__(256) void k_qkvs2(const float* __restrict__ h, const u16* __restrict__ swb,
    const float* __restrict__ qb, u16* __restrict__ Qg, u16* __restrict__ Kg, u16* __restrict__ Vg) {
  int l = threadIdx.x & 63, wv = threadIdx.x >> 6;
  int lm = l & 15, lk = l >> 4;
  long t0 = (long)blockIdx.x * 64 + wv * 16;
  const float* hp = h + (t0 + lm) * 64;
  s16x8 A[2];
#pragma unroll
  for (int ks = 0; ks < 2; ks++) {
    float4 x0 = *(const float4*)(hp + ks * 32 + lk * 8);
    float4 x1 = *(const float4*)(hp + ks * 32 + lk * 8 + 4);
    s16x8 a;
    a[0] = (short)f2b(x0.x); a[1] = (short)f2b(x0.y); a[2] = (short)f2b(x0.z); a[3] = (short)f2b(x0.w);
    a[4] = (short)f2b(x1.x); a[5] = (short)f2b(x1.y); a[6] = (short)f2b(x1.z); a[7] = (short)f2b(x1.w);
    A[ks] = a;
  }
  f32x4 C[12];
#pragma unroll
  for (int nt = 0; nt < 12; nt++) C[nt] = (f32x4){0.f, 0.f, 0.f, 0.f};
#pragma unroll
  for (int ks = 0; ks < 2; ks++) {
#pragma unroll
    for (int nt = 0; nt < 12; nt++) {
      s16x8 B = *(const s16x8*)&swb[((nt * 2 + ks) * 16 + lm) * 32 + lk * 8];
      C[nt] = __builtin_amdgcn_mfma_f32_16x16x32_bf16(A[ks], B, C[nt], 0, 0, 0);
    }
  }
  float qbv[12];
#pragma unroll
  for (int nt = 0; nt < 12; nt++) qbv[nt] = qb[nt * 16 + lm];
#pragma unroll
  for (int r = 0; r < 4; r++) {
    long t = t0 + lk * 4 + r;
    int b = (int)(t / 100352); int r1 = (int)(t - (long)b * 100352);
    int d = r1 / 12544; int r2 = r1 - d * 12544;
    int hy = r2 / 112, wx = r2 - hy * 112;
    int d0 = d >> 1, dz = d & 1, h0 = hy / 7, oy = hy - h0 * 7, w0 = wx / 7, ox = wx - w0 * 7;
    int wi = ((b * 4 + d0) * 16 + h0) * 16 + w0;
    int n = dz * 49 + oy * 7 + ox;
    long base = (long)(wi * 4) * 1568 + n * 16 + lm;
#pragma unroll
    for (int nt = 0; nt < 12; nt++) {
      int part = nt >> 2, hd = nt & 3;
      float v = C[nt][r] + qbv[nt];
      long o = base + hd * 1568;
      if (part == 0) Qg[o] = f2b(v * 0.25f);
      else if (part == 1) Kg[o] = f2b(v);
      else Vg[o] = f2b(v);
    }
  }
}

// ---------------- MFMA spatial attention + fused projection: 1 block per window -
// 8 waves x 1 m-tile (wave 7 stages only); bias from precomputed table Bt.
__global__ __launch_bounds__(512) void k_sattn3(const u16* __restrict__ Qg, const u16* __restrict__ Kg,
    const u16* __restrict__ Vg, const float* __restrict__ Bt, const u16* __restrict__ pwb,
    const float* __restrict__ pb, float* __restrict__ accg) {
  __shared__ __align__(16) u16 sQ[112 * 24];
  __shared__ __align__(16) u16 sK[112 * 24];
  __shared__ __align__(16) u16 sVt[16 * 136];
  __shared__ __align__(16) u16 sP[112 * 120 + 32];
  __shared__ __align__(16) u16 sO[112 * 24];
  int tid = threadIdx.x;
  int wi = blockIdx.x;
  int l = tid & 63, wv = tid >> 6;
  int lm = l & 15, lk = l >> 4;

  for (int i = tid; i < 336; i += 512) { sQ[2352 + i] = 0; sK[2352 + i] = 0; }       // rows 98..111
  for (int i = tid; i < 224; i += 512) { sVt[(i / 14) * 136 + 98 + (i % 14)] = 0; }  // V^T cols 98..111

  int mt = wv;                 // 0..7; wave 7 compute-idle
  bool act = mt < 7;
  int baserow = mt * 16 + lk * 4;
  f32x4 po[4];
#pragma unroll
  for (int b = 0; b < 4; b++) po[b] = (f32x4){0.f, 0.f, 0.f, 0.f};

  for (int hd = 0; hd < 4; hd++) {
    __syncthreads();
    long base = (long)(wi * 4 + hd) * 1568;
    const u32* qp = (const u32*)(Qg + base);
    const u32* kp = (const u32*)(Kg + base);
    const u32* vp = (const u32*)(Vg + base);
    for (int i = tid; i < 784; i += 512) {
      u32 v = qp[i];
      int n = i >> 3, j2 = (i & 7) * 2;
      *(u32*)&sQ[n * 24 + j2] = v;
    }
    for (int i = tid; i < 784; i += 512) {
      u32 v = kp[i];
      int n = i >> 3, j2 = (i & 7) * 2;
      *(u32*)&sK[n * 24 + j2] = v;
    }
    for (int i = tid; i < 784; i += 512) {
      u32 v = vp[i];
      int n = i >> 3, j2 = (i & 7) * 2;
      sVt[j2 * 136 + n] = (u16)(v & 0xffffu);
      sVt[(j2 + 1) * 136 + n] = (u16)(v >> 16);
    }
    __syncthreads();
    if (!act) continue;

    // ---- QK^T (K=16 zero-padded to 32 via lk<2 masking) ----
    s16x8 Aq = {};
    if (lk < 2) Aq = *(const s16x8*)&sQ[(mt * 16 + lm) * 24 + lk * 8];
    f32x4 S[7];
#pragma unroll
    for (int nt = 0; nt < 7; nt++) {
      s16x8 Bk = {};
      if (lk < 2) Bk = *(const s16x8*)&sK[(nt * 16 + lm) * 24 + lk * 8];
      S[nt] = __builtin_amdgcn_mfma_f32_16x16x32_bf16(Aq, Bk, (f32x4){0.f, 0.f, 0.f, 0.f}, 0, 0, 0);
    }
    // ---- bias (coalesced table loads) + softmax ----
    const float* bt = Bt + hd * 12544 + baserow * 112 + lm;
    float mx0 = -3e38f, mx1 = -3e38f, mx2 = -3e38f, mx3 = -3e38f;
#pragma unroll
    for (int nt = 0; nt < 7; nt++) {
      S[nt][0] += bt[nt * 16];
      S[nt][1] += bt[112 + nt * 16];
      S[nt][2] += bt[224 + nt * 16];
      S[nt][3] += bt[336 + nt * 16];
      mx0 = fmaxf(mx0, S[nt][0]); mx1 = fmaxf(mx1, S[nt][1]);
      mx2 = fmaxf(mx2, S[nt][2]); mx3 = fmaxf(mx3, S[nt][3]);
    }
#pragma unroll
    for (int off = 1; off < 16; off <<= 1) {
      mx0 = fmaxf(mx0, __shfl_xor(mx0, off));
      mx1 = fmaxf(mx1, __shfl_xor(mx1, off));
      mx2 = fmaxf(mx2, __shfl_xor(mx2, off));
      mx3 = fmaxf(mx3, __shfl_xor(mx3, off));
    }
    float s0 = 0.f, s1 = 0.f, s2 = 0.f, s3 = 0.f;
#pragma unroll
    for (int nt = 0; nt < 7; nt++) {
      S[nt][0] = __expf(S[nt][0] - mx0); s0 += S[nt][0];
      S[nt][1] = __expf(S[nt][1] - mx1); s1 += S[nt][1];
      S[nt][2] = __expf(S[nt][2] - mx2); s2 += S[nt][2];
      S[nt][3] = __expf(S[nt][3] - mx3); s3 += S[nt][3];
    }
#pragma unroll
    for (int off = 1; off < 16; off <<= 1) {
      s0 += __shfl_xor(s0, off); s1 += __shfl_xor(s1, off);
      s2 += __shfl_xor(s2, off); s3 += __shfl_xor(s3, off);
    }
    float i0 = 1.f / s0, i1 = 1.f / s1, i2 = 1.f / s2, i3 = 1.f / s3;
#pragma unroll
    for (int nt = 0; nt < 7; nt++) {
      int c = nt * 16 + lm;
      sP[(baserow + 0) * 120 + c] = f2b(S[nt][0] * i0);
      sP[(baserow + 1) * 120 + c] = f2b(S[nt][1] * i1);
      sP[(baserow + 2) * 120 + c] = f2b(S[nt][2] * i2);
      sP[(baserow + 3) * 120 + c] = f2b(S[nt][3] * i3);
    }
    // ---- PV: k=0..95 unmasked (in-row), k=96..127 masked ----
    int rowoff = (mt * 16 + lm) * 120;
    f32x4 pv = (f32x4){0.f, 0.f, 0.f, 0.f};
#pragma unroll
    for (int ks = 0; ks < 3; ks++) {
      s16x8 Ap = *(const s16x8*)&sP[rowoff + ks * 32 + lk * 8];
      s16x8 Bv = *(const s16x8*)&sVt[lm * 136 + ks * 32 + lk * 8];
      pv = __builtin_amdgcn_mfma_f32_16x16x32_bf16(Ap, Bv, pv, 0, 0, 0);
    }
    {
      s16x8 Ap = {}, Bv = {};
      if (lk < 2) {
        Ap = *(const s16x8*)&sP[rowoff + 96 + lk * 8];
        Bv = *(const s16x8*)&sVt[lm * 136 + 96 + lk * 8];
      }
      pv = __builtin_amdgcn_mfma_f32_16x16x32_bf16(Ap, Bv, pv, 0, 0, 0);
    }
#pragma unroll
    for (int r = 0; r < 4; r++) sO[(baserow + r) * 24 + lm] = f2b(pv[r]);
    // ---- per-head proj into po (K=16 pad 32) ----
    s16x8 Ao = {};
    if (lk < 2) Ao = *(const s16x8*)&sO[(mt * 16 + lm) * 24 + lk * 8];
#pragma unroll
    for (int nt = 0; nt < 4; nt++) {
      s16x8 Bw = {};
      if (lk < 2) Bw = *(const s16x8*)&pwb[((((hd * 4 + nt) * 2 + lk) * 16 + lm) * 8)];
      po[nt] = __builtin_amdgcn_mfma_f32_16x16x32_bf16(Ao, Bw, po[nt], 0, 0, 0);
    }
  }
  // ---- epilogue: acc[p*64+col] += po + pb ----
  if (act) {
    int b = wi >> 10, d0 = (wi >> 8) & 3, h0 = (wi >> 4) & 15, w0 = wi & 15;
    float pbv[4];
#pragma unroll
    for (int nt = 0; nt < 4; nt++) pbv[nt] = pb[nt * 16 + lm];
#pragma unroll
    for (int r = 0; r < 4; r++) {
      int n = mt * 16 + lk * 4 + r;
      if (n >= 98) continue;
      int dz = n / 49, rr = n - dz * 49, oy = rr / 7, ox = rr - oy * 7;
      long p = ((long)(b * 8 + d0 * 2 + dz) * 112 + (h0 * 7 + oy)) * 112 + (w0 * 7 + ox);
      float* ap = accg + p * 64;
#pragma unroll
      for (int nt = 0; nt < 4; nt++) {
        int col = nt * 16 + lm;
        ap[col] += po[nt][r] + pbv[nt];
      }
    }
  }
}

// ---------------- Temporal qkv: MFMA dense GEMM M=200704 N=96 K=64 --------------
__global__ __launch_bounds__(256) void k_qkvt(const float* __restrict__ h, const u16* __restrict__ twb,
    const float* __restrict__ qb, u16* __restrict__ T) {
  int l = threadIdx.x & 63, wv = threadIdx.x >> 6;
  int lm = l & 15, lk = l >> 4;
  long t0 = (long)blockIdx.x * 64 + wv * 16;
  const float* hp = h + (t0 + lm) * 64;
  s16x8 A[2];
#pragma unroll
  for (int ks = 0; ks < 2; ks++) {
    float4 x0 = *(const float4*)(hp + ks * 32 + lk * 8);
    float4 x1 = *(const float4*)(hp + ks * 32 + lk * 8 + 4);
    s16x8 a;
    a[0] = (short)f2b(x0.x); a[1] = (short)f2b(x0.y); a[2] = (short)f2b(x0.z); a[3] = (short)f2b(x0.w);
    a[4] = (short)f2b(x1.x); a[5] = (short)f2b(x1.y); a[6] = (short)f2b(x1.z); a[7] = (short)f2b(x1.w);
    A[ks] = a;
  }
  f32x4 C[6];
#pragma unroll
  for (int nt = 0; nt < 6; nt++) C[nt] = (f32x4){0.f, 0.f, 0.f, 0.f};
#pragma unroll
  for (int ks = 0; ks < 2; ks++) {
#pragma unroll
    for (int nt = 0; nt < 6; nt++) {
      s16x8 B = *(const s16x8*)&twb[((nt * 2 + ks) * 16 + lm) * 32 + lk * 8];
      C[nt] = __builtin_amdgcn_mfma_f32_16x16x32_bf16(A[ks], B, C[nt], 0, 0, 0);
    }
  }
  float qbv[6];
#pragma unroll
  for (int nt = 0; nt < 6; nt++) qbv[nt] = qb[nt * 16 + lm];
#pragma unroll
  for (int r = 0; r < 4; r++) {
    long t = t0 + lk * 4 + r;
    int bb = (int)(t / 100352); int r1 = (int)(t - (long)bb * 100352);
    int d = r1 / 12544; int rr = r1 - d * 12544;
    long sidx = ((long)(bb * 12544 + rr) * 8 + d) * 96;
#pragma unroll
    for (int nt = 0; nt < 6; nt++) {
      int ch = nt * 16 + lm;
      float v = C[nt][r] + qbv[nt];
      if (nt < 2) v *= 0.25f;
      T[sidx + ch] = f2b(v);
    }
  }
}

// ---------------- Temporal attention (per pixel-seq, D=8) + proj, acc += --------
__global__ __launch_bounds__(256) void k_tattn2(const u16* __restrict__ T, const float* __restrict__ rpbt,
    const float* __restrict__ pw, const float* __restrict__ pb, float* __restrict__ acc) {
  __shared__ float sm[4][1064];   // sq 8x100, o 8x33
  int wv = threadIdx.x >> 6, lane = threadIdx.x & 63;
  int s = blockIdx.x * 4 + wv;
  int b = s / 12544, rr = s - b * 12544;
  float* sq = sm[wv];
  float* o = sq + 800;
  const u32* Tp = (const u32*)(T + (long)s * 768);
  for (int i = lane; i < 192; i += 64) {
    u32 lo = Tp[i * 2], hi = Tp[i * 2 + 1];
    int d = i / 24, base = (i - d * 24) * 4;
    float* dst = sq + d * 100 + base;
    dst[0] = bflo(lo); dst[1] = bfhi(lo); dst[2] = bflo(hi); dst[3] = bfhi(hi);
  }
  __syncthreads();
  if (lane < 32) {
    int hd = lane >> 3, n = lane & 7;
    const float* qr = sq + n * 100 + hd * 8;
    float p[8];
    float mx = -3e38f;
#pragma unroll
    for (int m = 0; m < 8; m++) {
      const float* kr = sq + m * 100 + 32 + hd * 8;
      float sc = 0.f;
#pragma unroll
      for (int e = 0; e < 8; e++) sc += qr[e] * kr[e];
      sc += rpbt[(n - m + 7) * 4 + hd];
      p[m] = sc; mx = fmaxf(mx, sc);
    }
    float sum = 0.f;
#pragma unroll
    for (int m = 0; m < 8; m++) { p[m] = __expf(p[m] - mx); sum += p[m]; }
    float inv = 1.f / sum;
#pragma unroll
    for (int j = 0; j < 8; j++) {
      float oj = 0.f;
#pragma unroll
      for (int m = 0; m < 8; m++) oj += p[m] * sq[m * 100 + 64 + hd * 8 + j];
      o[n * 33 + hd * 8 + j] = oj * inv;
    }
  }
  __syncthreads();
  float a[8];
  float pbc = pb[lane];
#pragma unroll
  for (int n = 0; n < 8; n++) a[n] = pbc;
  for (int k = 0; k < 32; k++) {
    float w = pw[k * 64 + lane];
#pragma unroll
    for (int n = 0; n < 8; n++) a[n] += o[n * 33 + k] * w;
  }
  long base = ((long)b * 100352 + rr) * 64 + lane;
#pragma unroll
  for (int n = 0; n < 8; n++) acc[base + (long)n * 802816] += a[n];
}

// ---------------- Weight prepack: OIDHW f32 -> WB[kk][co][ci] bf16 --------------
__global__ __launch_bounds__(256) void k_wprep(const float* __restrict__ w0, const float* __restrict__ w1,
    const float* __restrict__ w2, const float* __restrict__ w3, u16* __restrict__ WB) {
  int c = blockIdx.y;
  int i = blockIdx.x * 256 + threadIdx.x;   // < 27648
  const float* src = c == 0 ? w0 : c == 1 ? w1 : c == 2 ? w2 : w3;
  int co = i / 864, rem = i - co * 864, ci = rem / 27, kk = rem - ci * 27;
  WB[c * 27648 + kk * 1024 + co * 32 + ci] = f2b(src[i]);
}

// ---------------- MFMA implicit-GEMM 3x3x3 conv, 32ci->32co, bf16 in, fp32 acc --
__global__ __launch_bounds__(64) void k_convm(const u16* __restrict__ in, const u16* __restrict__ wb,
    const float* __restrict__ bias, int mode,
    const float* __restrict__ hbuf, const float* __restrict__ accb,
    float* __restrict__ dout, float* __restrict__ x2f, u16* __restrict__ outb) {
  int row = blockIdx.x;
  int hh = row % 112, bz = row / 112;
  int d = bz & 7, bb = bz >> 3;
  long prow = (long)row * 112;
  int l = threadIdx.x, lm = l & 15, lk = l >> 4;
  f32x4 acc[7][2];
#pragma unroll
  for (int t = 0; t < 7; t++) { acc[t][0] = (f32x4){0.f,0.f,0.f,0.f}; acc[t][1] = (f32x4){0.f,0.f,0.f,0.f}; }
  for (int kd = 0; kd < 3; kd++) {
    int zd = d + kd - 1;
    if (zd < 0 || zd > 7) continue;
    for (int kh = 0; kh < 3; kh++) {
      int yy = hh + kh - 1;
      if (yy < 0 || yy > 111) continue;
      const u16* ip = in + ((long)((bb * 8 + zd) * 112 + yy)) * 112 * 32;
      int kkb = kd * 9 + kh * 3;
      s16x8 B0[3], B1[3];
#pragma unroll
      for (int kw = 0; kw < 3; kw++) {
        const u16* wp = wb + (kkb + kw) * 1024 + lk * 8;
        B0[kw] = *(const s16x8*)(wp + lm * 32);
        B1[kw] = *(const s16x8*)(wp + (16 + lm) * 32);
      }
#pragma unroll
      for (int t = 0; t < 7; t++) {
#pragma unroll
        for (int kw = 0; kw < 3; kw++) {
          int w = t * 16 + lm + kw - 1;
          s16x8 A = {};
          if ((unsigned)w < 112u) A = *(const s16x8*)(ip + (long)w * 32 + lk * 8);
          acc[t][0] = __builtin_amdgcn_mfma_f32_16x16x32_bf16(A, B0[kw], acc[t][0], 0, 0, 0);
          acc[t][1] = __builtin_amdgcn_mfma_f32_16x16x32_bf16(A, B1[kw], acc[t][1], 0, 0, 0);
        }
      }
    }
  }
  float b0 = bias[lm], b1 = bias[16 + lm];
#pragma unroll
  for (int t = 0; t < 7; t++) {
#pragma unroll
    for (int r = 0; r < 4; r++) {
      long pos = prow + t * 16 + lk * 4 + r;
      float v0 = acc[t][0][r] + b0;
      float v1 = acc[t][1][r] + b1;
      if (mode == 1) {
        v0 = v0 > 0.f ? v0 : 0.01f * v0;
        v1 = v1 > 0.f ? v1 : 0.01f * v1;
        outb[pos * 32 + lm] = f2b(v0);
        outb[pos * 32 + 16 + lm] = f2b(v1);
      } else if (mode == 2) {
        float y0 = v0 + hbuf[pos * 64 + lm];
        float y1v = v1 + hbuf[pos * 64 + 16 + lm];
        dout[pos * 64 + lm] = accb[pos * 64 + lm] + y0;
        dout[pos * 64 + 16 + lm] = accb[pos * 64 + 16 + lm] + y1v;
        float t0 = hbuf[pos * 64 + 32 + lm] + y0;
        float t1 = hbuf[pos * 64 + 48 + lm] + y1v;
        x2f[pos * 32 + lm] = t0;
        x2f[pos * 32 + 16 + lm] = t1;
        outb[pos * 32 + lm] = f2b(t0);
        outb[pos * 32 + 16 + lm] = f2b(t1);
      } else {
        float y0 = v0 + x2f[pos * 32 + lm];
        float y1v = v1 + x2f[pos * 32 + 16 + lm];
        dout[pos * 64 + 32 + lm] = accb[pos * 64 + 32 + lm] + y0;
        dout[pos * 64 + 48 + lm] = accb[pos * 64 + 48 + lm] + y1v;
      }
    }
  }
}

extern "C" void kernel_launch(void* const* d_in, const int* in_sizes, int n_in,
                              void* d_out, int out_size, void* d_ws, size_t ws_size,
                              hipStream_t stream) {
  const float* x        = (const float*)d_in[0];
  // d_in[1] mask_matrix: unused (all zeros; reference never applies it)
  const float* g1       = (const float*)d_in[2];
  const float* b1       = (const float*)d_in[3];
  const float* rpb_s    = (const float*)d_in[4];
  const float* qkv_w_s  = (const float*)d_in[5];
  const float* qkv_b_s  = (const float*)d_in[6];
  const float* proj_w_s = (const float*)d_in[7];
  const float* proj_b_s = (const float*)d_in[8];
  const float* rpb_t    = (const float*)d_in[9];
  const float* qkv_w_t  = (const float*)d_in[10];
  const float* qkv_b_t  = (const float*)d_in[11];
  const float* proj_w_t = (const float*)d_in[12];
  const float* proj_b_t = (const float*)d_in[13];
  const float* g2       = (const float*)d_in[14];
  const float* b2       = (const float*)d_in[15];
  const float* c1w = (const float*)d_in[16];
  const float* c1b = (const float*)d_in[17];
  const float* c2w = (const float*)d_in[18];
  const float* c2b = (const float*)d_in[19];
  const float* c3w = (const float*)d_in[20];
  const float* c3b = (const float*)d_in[21];
  const float* c4w = (const float*)d_in[22];
  const float* c4b = (const float*)d_in[23];

  // workspace (fp32 elems): acc(12.8M) | hbuf(12.8M) | creg(19.27M)
  float* acc  = (float*)d_ws;
  float* hbuf = acc + 12845056;
  float* creg = hbuf + 12845056;
  u16* Qg = (u16*)creg;
  u16* Kg = Qg + 12845056;
  u16* Vg = Kg + 12845056;
  u16* Tt = (u16*)creg;                // temporal qkv, after sattn3
  u16* x1b = (u16*)creg;               // conv phase
  u16* t_b = x1b + 6422528;
  u16* x2b = t_b + 6422528;
  float* x2f = (float*)(x2b + 6422528);
  u16* WB = (u16*)(x2f + 6422528);
  float* dout = (float*)d_out;
  // d_out scratch (dead until conv2 writes at step 9):
  u16* pwb = (u16*)d_out;              // 4096 u16
  u16* twb = (u16*)d_out + 4096;       // 6144 u16
  u16* swb = (u16*)d_out + 10240;      // 12288 u16 -> ends 22528 u16 = 45056 B
  float* Bt = (float*)d_out + 11264;   // 50176 f32 (200 KB)

  // 0. prepacks + bias table into d_out scratch
  k_pwprep<<<16, 256, 0, stream>>>(proj_w_s, pwb);
  k_twprep<<<24, 256, 0, stream>>>(qkv_w_t, twb);
  k_swprep<<<48, 256, 0, stream>>>(qkv_w_s, swb);
  k_bprep<<<196, 256, 0, stream>>>(rpb_s, Bt);
  // 1. LN1: h = LN(x); acc = x
  k_ln<<<50176, 256, 0, stream>>>(x, g1, b1, hbuf, acc, nullptr);
  // 2. spatial qkv (MFMA GEMM) -> bf16 windowed Q/K/V
  k_qkvs2<<<3136, 256, 0, stream>>>(hbuf, swb, qkv_b_s, Qg, Kg, Vg);
  // 3. MFMA spatial attention + fused projection, acc +=
  k_sattn3<<<2048, 512, 0, stream>>>(Qg, Kg, Vg, Bt, pwb, proj_b_s, acc);
  // 4. temporal qkv (MFMA dense) -> Tt (overlaps dead Qg/Kg)
  k_qkvt<<<3136, 256, 0, stream>>>(hbuf, twb, qkv_b_t, Tt);
  // 5. temporal attention + proj, acc +=
  k_tattn2<<<6272, 256, 0, stream>>>(Tt, rpb_t, proj_w_t, proj_b_t, acc);
  // 6. conv weight prepack
  k_wprep<<<dim3(108, 4), 256, 0, stream>>>(c1w, c2w, c3w, c4w, WB);
  // 7. LN2: h2 = LN(acc) -> hbuf f32 + x1b bf16 (ch 0..31)
  k_ln<<<50176, 256, 0, stream>>>(acc, g2, b2, hbuf, nullptr, x1b);
  // 8. conv path 1: t = lrelu(conv(x1)) -> t_b bf16
  k_convm<<<1792, 64, 0, stream>>>(x1b, WB, c1b, 1, nullptr, nullptr, nullptr, nullptr, t_b);
  // 9. conv2 + fused: y1 = x1 + conv(t); dout(ch0..31)=acc+y1; x2f/x2b = h2[32:]+y1
  k_convm<<<1792, 64, 0, stream>>>(t_b, WB + 27648, c2b, 2, hbuf, acc, dout, x2f, x2b);
  // 10. conv path 2: t = lrelu(conv(x2b)) -> t_b bf16
  k_convm<<<1792, 64, 0, stream>>>(x2b, WB + 2 * 27648, c3b, 1, nullptr, nullptr, nullptr, nullptr, t_b);
  // 11. conv4 + fused: y2 = x2 + conv(t); dout(ch32..63) = acc + y2
  k_convm<<<1792, 64, 0, stream>>>(t_b, WB + 3 * 27648, c4b, 4, nullptr, acc, dout, x2f, nullptr);
}